// Round 6
// baseline (813.322 us; speedup 1.0000x reference)
//
#include <hip/hip_runtime.h>
#include <hip/hip_bf16.h>
#include <math.h>

#define NN 50000
#define NG 128
#define INC 128
#define HIDC 256
#define NCLS 10

#define NBLK 256   // partition chunks
#define BSH 8      // bucket = col >> 8
#define NB 196     // ceil(50000/256) buckets

typedef __attribute__((ext_vector_type(8))) short s8_t;    // 8 bf16 (4 VGPR)
typedef __attribute__((ext_vector_type(4))) float f4_t;    // 4 f32

__device__ inline f4_t mfma16(s8_t a, s8_t b, f4_t c) {
  return __builtin_amdgcn_mfma_f32_16x16x32_bf16(a, b, c, 0, 0, 0);
}

__device__ inline float bf2f(ushort u) {
  union { unsigned int i; float f; } c; c.i = ((unsigned int)u) << 16; return c.f;
}
__device__ inline ushort f2bf(float f) {
  __hip_bfloat16 h = __float2bfloat16(f);
  return *(ushort*)&h;
}
__device__ inline unsigned packbf(float a, float b) {
  return (unsigned)f2bf(a) | ((unsigned)f2bf(b) << 16);
}

__device__ inline void gload_lds16(const void* g, void* l) {
  __builtin_amdgcn_global_load_lds(
      (const __attribute__((address_space(1))) unsigned int*)g,
      (__attribute__((address_space(3))) unsigned int*)l, 16, 0, 0);
}

// ---------------- bucketed edge partition ----------------
__global__ __launch_bounds__(256) void edge_hist(const int* __restrict__ ecol,
                                                 int* __restrict__ hist, int E, int chunk) {
  __shared__ int h[NB];
  int blk = blockIdx.x;
  for (int i = threadIdx.x; i < NB; i += 256) h[i] = 0;
  __syncthreads();
  int e0 = blk * chunk, e1 = min(e0 + chunk, E);
  for (int e = e0 + threadIdx.x; e < e1; e += 256)
    atomicAdd(&h[ecol[e] >> BSH], 1);
  __syncthreads();
  for (int i = threadIdx.x; i < NB; i += 256) hist[i * NBLK + blk] = h[i];
}

// part entry: (row << 8) | (col & 255)
__global__ __launch_bounds__(256) void edge_partition(const int* __restrict__ erow,
                                                      const int* __restrict__ ecol,
                                                      const int* __restrict__ histBase,
                                                      unsigned* __restrict__ part,
                                                      int E, int chunk) {
  __shared__ int cur[NB];
  int blk = blockIdx.x;
  for (int i = threadIdx.x; i < NB; i += 256) cur[i] = histBase[i * NBLK + blk];
  __syncthreads();
  int e0 = blk * chunk, e1 = min(e0 + chunk, E);
  for (int e = e0 + threadIdx.x; e < e1; e += 256) {
    int c = ecol[e];
    int b = c >> BSH;
    int pos = atomicAdd(&cur[b], 1);
    part[pos] = ((unsigned)erow[e] << 8) | (unsigned)(c & 255);
  }
}

__global__ __launch_bounds__(256) void bucket_deg_dis(const unsigned* __restrict__ part,
                                                      const int* __restrict__ histBase,
                                                      int* __restrict__ deg,
                                                      float* __restrict__ dis, int N) {
  __shared__ int cnt[256];
  int b = blockIdx.x;
  cnt[threadIdx.x] = 0;
  __syncthreads();
  int s0 = histBase[b * NBLK];
  int s1 = histBase[(b + 1) * NBLK];
  for (int e = s0 + threadIdx.x; e < s1; e += 256)
    atomicAdd(&cnt[part[e] & 255], 1);
  __syncthreads();
  int node = (b << BSH) + threadIdx.x;
  if (node < N) {
    int d = cnt[threadIdx.x];
    deg[node] = d;
    dis[node] = rsqrtf((float)d + 1.0f);
  }
}

__global__ __launch_bounds__(256) void bucket_csr(const unsigned* __restrict__ part,
                                                  const int* __restrict__ histBase,
                                                  const int* __restrict__ offsets,
                                                  int* __restrict__ rows_csr, int N) {
  __shared__ int cur[256];
  int b = blockIdx.x;
  int node = (b << BSH) + threadIdx.x;
  cur[threadIdx.x] = (node < N) ? offsets[node] : 0;
  __syncthreads();
  int s0 = histBase[b * NBLK];
  int s1 = histBase[(b + 1) * NBLK];
  for (int e = s0 + threadIdx.x; e < s1; e += 256) {
    unsigned pv = part[e];
    int pos = atomicAdd(&cur[pv & 255], 1);
    rows_csr[pos] = (int)(pv >> 8);
  }
}

// ---------------- multi-block exclusive scan ----------------
#define SCAN_T 256
#define SCAN_V 8
#define SCAN_VPB (SCAN_T * SCAN_V)  // 2048

__global__ __launch_bounds__(SCAN_T) void scanA(const int* __restrict__ deg,
                                                int* __restrict__ offsets,
                                                int* __restrict__ blockTotals, int n) {
  __shared__ int sm[SCAN_T];
  int b = blockIdx.x;
  int t = threadIdx.x;
  int base = b * SCAN_VPB + t * SCAN_V;
  int v[SCAN_V];
  int run = 0;
  #pragma unroll
  for (int j = 0; j < SCAN_V; ++j) {
    int idx = base + j;
    int d = (idx < n) ? deg[idx] : 0;
    run += d;
    v[j] = run;
  }
  sm[t] = run;
  __syncthreads();
  #pragma unroll
  for (int off = 1; off < SCAN_T; off <<= 1) {
    int x = (t >= off) ? sm[t - off] : 0;
    __syncthreads();
    sm[t] += x;
    __syncthreads();
  }
  int excl = (t == 0) ? 0 : sm[t - 1];
  #pragma unroll
  for (int j = 0; j < SCAN_V; ++j) {
    int idx = base + j;
    if (idx < n) offsets[idx + 1] = v[j] + excl;
  }
  if (t == SCAN_T - 1) blockTotals[b] = sm[t];
}

__global__ void scanB(int* __restrict__ blockTotals, int nb) {
  if (threadIdx.x == 0 && blockIdx.x == 0) {
    int run = 0;
    for (int i = 0; i < nb; ++i) {
      int v = blockTotals[i];
      blockTotals[i] = run;
      run += v;
    }
  }
}

__global__ void scanC(int* __restrict__ offsets, const int* __restrict__ blockTotals, int n) {
  int stride = gridDim.x * blockDim.x;
  for (int i = blockIdx.x * blockDim.x + threadIdx.x; i < n; i += stride) {
    offsets[i + 1] += blockTotals[i / SCAN_VPB];
    if (i == 0) offsets[0] = 0;
  }
}

// ---------------- casts ----------------
// x [N][128] f32 -> x_cb [4][N][16 uints] (cb-blocked bf16 pairs)
__global__ void cast_x_cb(const float* __restrict__ x, unsigned* __restrict__ xcb, int N) {
  int t = blockIdx.x * 256 + threadIdx.x;
  if (t >= N * 64) return;
  int n = t >> 6, pp = t & 63;  // pp = channel pair 0..63
  float v0 = x[(long)n * 128 + 2 * pp];
  float v1 = x[(long)n * 128 + 2 * pp + 1];
  xcb[((long)(pp >> 4) * N + n) * 16 + (pp & 15)] = packbf(v0, v1);
}

// fused transpose+cast of W1 [128,256] and W2 [256,256]
__global__ void transpose_cast2(const float* __restrict__ W1, ushort* __restrict__ W1T,
                                const float* __restrict__ W2, ushort* __restrict__ W2T) {
  int idx = blockIdx.x * blockDim.x + threadIdx.x;
  if (idx < INC * HIDC) {
    int k = idx / HIDC, n = idx % HIDC;
    W1T[(long)n * INC + k] = f2bf(W1[idx]);
  }
  int i2 = idx - INC * HIDC;
  if (i2 >= 0 && i2 < HIDC * HIDC) {
    int k = i2 / HIDC, n = i2 % HIDC;
    W2T[(long)n * HIDC + k] = f2bf(W2[i2]);
  }
}

// ---------------- channel-blocked aggregation ----------------
// grid: (ceil(N/4), n_cb). One wave per node per cb-slice (32 channels).
// 4 edge-groups x 16 lanes; each group gathers 64B coalesced per edge.
__global__ __launch_bounds__(256) void aggregate_cb(
    const unsigned* __restrict__ xcb, const float* __restrict__ dis,
    const int* __restrict__ offsets, const int* __restrict__ rows_csr,
    unsigned* __restrict__ outcb, int N) {
  int node = blockIdx.x * 4 + (threadIdx.x >> 6);
  if (node >= N) return;
  int lane = threadIdx.x & 63;
  int g = lane >> 4;      // edge group 0..3
  int cl = lane & 15;     // channel pair 0..15
  long cbN = (long)blockIdx.y * N;
  float di = dis[node];
  float a0 = 0.0f, a1 = 0.0f;
  if (g == 0) {
    unsigned sv = xcb[(cbN + node) * 16 + cl];
    a0 = bf2f((ushort)sv) * di * di;
    a1 = bf2f((ushort)(sv >> 16)) * di * di;
  }
  int e0 = offsets[node], e1 = offsets[node + 1];
  for (int e = e0 + g; e < e1; e += 4) {
    int src = rows_csr[e];
    float s = dis[src] * di;
    unsigned v = xcb[(cbN + src) * 16 + cl];
    a0 = fmaf(bf2f((ushort)v), s, a0);
    a1 = fmaf(bf2f((ushort)(v >> 16)), s, a1);
  }
  a0 += __shfl_xor(a0, 16); a0 += __shfl_xor(a0, 32);
  a1 += __shfl_xor(a1, 16); a1 += __shfl_xor(a1, 32);
  if (lane < 16) outcb[(cbN + node) * 16 + cl] = packbf(a0, a1);
}

// ---------------- MFMA GEMM (round-4 shape: 128x128 tile, grid.y=2) ----------------
// A in cb layout [K/32][M][32] bf16; WT row-major [256][K] bf16.
// OUTCB: write h in cb layout [8][M][32]; else row-major [M][256].
template <int K, bool OUTCB>
__global__ __launch_bounds__(256) void gemm_mfma(
    const ushort* __restrict__ A, const ushort* __restrict__ WT,
    const float* __restrict__ bias, ushort* __restrict__ outb, int M) {
  __shared__ ushort smem[16384];  // 32 KB: A at 0, B at 8192
  const int tid = threadIdx.x;
  const int lane = tid & 63;
  const int wave = tid >> 6;
  const int wm = wave >> 1, wn = wave & 1;
  const int m0 = blockIdx.x * 128;
  const int n0 = blockIdx.y * 128;

  f4_t acc[4][4] = {};

  for (int k0 = 0; k0 < K; k0 += 64) {
    __syncthreads();
    // stage A tile [128][64]: LDS slot s -> logical row=s>>3, chunk=(s&7)^(row&7)
    #pragma unroll
    for (int is = 0; is < 4; ++is) {
      int s = is * 256 + tid;
      int row = s >> 3;
      int ch = (s & 7) ^ (row & 7);
      int k = k0 + ch * 8;
      long grow = m0 + row; if (grow > M - 1) grow = M - 1;
      const ushort* g = A + ((long)(k >> 5) * M + grow) * 32 + (k & 31);
      gload_lds16(g, &smem[(is * 256 + wave * 64) * 8]);
    }
    // stage B tile (WT rows n0..n0+127)
    #pragma unroll
    for (int is = 0; is < 4; ++is) {
      int s = is * 256 + tid;
      int row = s >> 3;
      int ch = (s & 7) ^ (row & 7);
      const ushort* g = WT + (long)(n0 + row) * K + k0 + ch * 8;
      gload_lds16(g, &smem[8192 + (is * 256 + wave * 64) * 8]);
    }
    asm volatile("s_waitcnt vmcnt(0)" ::: "memory");
    __syncthreads();
    #pragma unroll
    for (int ks = 0; ks < 2; ++ks) {
      s8_t af[4], bfr[4];
      #pragma unroll
      for (int mi = 0; mi < 4; ++mi) {
        int row = wm * 64 + mi * 16 + (lane & 15);
        int ch = (ks * 4 + (lane >> 4)) ^ (row & 7);
        af[mi] = *(const s8_t*)(&smem[row * 64 + ch * 8]);
      }
      #pragma unroll
      for (int ni = 0; ni < 4; ++ni) {
        int row = wn * 64 + ni * 16 + (lane & 15);
        int ch = (ks * 4 + (lane >> 4)) ^ (row & 7);
        bfr[ni] = *(const s8_t*)(&smem[8192 + row * 64 + ch * 8]);
      }
      #pragma unroll
      for (int mi = 0; mi < 4; ++mi)
        #pragma unroll
        for (int ni = 0; ni < 4; ++ni)
          acc[mi][ni] = mfma16(af[mi], bfr[ni], acc[mi][ni]);
    }
  }
  // epilogue: D col=lane&15, row=(lane>>4)*4+r
  #pragma unroll
  for (int ni = 0; ni < 4; ++ni) {
    int col = n0 + wn * 64 + ni * 16 + (lane & 15);
    float bb = bias[col];
    #pragma unroll
    for (int mi = 0; mi < 4; ++mi) {
      #pragma unroll
      for (int r = 0; r < 4; ++r) {
        int row = m0 + wm * 64 + mi * 16 + (lane >> 4) * 4 + r;
        if (row < M) {
          float v = fmaxf(acc[mi][ni][r] + bb, 0.0f);
          if (OUTCB)
            outb[((long)(col >> 5) * M + row) * 32 + (col & 31)] = f2bf(v);
          else
            outb[(long)row * HIDC + col] = f2bf(v);
        }
      }
    }
  }
}

// ---------------- pool via sorted-batch ranges ----------------
__global__ void find_bounds(const int* __restrict__ batch, int* __restrict__ gstart, int n) {
  int stride = gridDim.x * blockDim.x;
  for (int i = blockIdx.x * blockDim.x + threadIdx.x; i < n; i += stride) {
    int b = batch[i];
    if (i == 0) {
      for (int g = 0; g <= b; ++g) gstart[g] = 0;
    } else {
      int pb = batch[i - 1];
      if (pb != b)
        for (int g = pb + 1; g <= b; ++g) gstart[g] = i;
    }
    if (i == n - 1) {
      for (int g = b + 1; g <= NG; ++g) gstart[g] = n;
    }
  }
}

#define POOL_SPLIT 8
__global__ __launch_bounds__(HIDC) void pool_range_bf16(const ushort* __restrict__ h,
                                                        const int* __restrict__ gstart,
                                                        float* __restrict__ gsum) {
  int g = blockIdx.x;
  int s = blockIdx.y;
  int c = threadIdx.x;
  int s0 = gstart[g], s1 = gstart[g + 1];
  int len = s1 - s0;
  int chunk = (len + POOL_SPLIT - 1) / POOL_SPLIT;
  int i0 = s0 + s * chunk;
  int i1 = min(i0 + chunk, s1);
  float acc = 0.0f;
  for (int i = i0; i < i1; ++i) acc += bf2f(h[(long)i * HIDC + c]);
  if (i1 > i0) atomicAdd(&gsum[g * HIDC + c], acc);
}

// ---------------- final MLP + log_softmax ----------------
__global__ __launch_bounds__(64) void mlp_kernel(
    const float* __restrict__ gsum, const int* __restrict__ gstart,
    const float* __restrict__ Wl1, const float* __restrict__ bl1,
    const float* __restrict__ Wl2, const float* __restrict__ bl2,
    float* __restrict__ out) {
  __shared__ float g[HIDC];
  __shared__ float hid[64];
  __shared__ float logits[NCLS];
  __shared__ float red[2];
  int i = blockIdx.x;
  int t = threadIdx.x;
  int cnt = gstart[i + 1] - gstart[i];
  float inv = 1.0f / fmaxf((float)cnt, 1.0f);
  for (int c = t; c < HIDC; c += 64) g[c] = gsum[i * HIDC + c] * inv;
  __syncthreads();
  float acc = bl1[t];
  for (int c = 0; c < HIDC; ++c) acc = fmaf(g[c], Wl1[c * 64 + t], acc);
  hid[t] = fmaxf(acc, 0.0f);
  __syncthreads();
  if (t < NCLS) {
    float l = bl2[t];
    for (int c = 0; c < 64; ++c) l = fmaf(hid[c], Wl2[c * NCLS + t], l);
    logits[t] = l;
  }
  __syncthreads();
  if (t == 0) {
    float m = -1e30f;
    for (int k = 0; k < NCLS; ++k) m = fmaxf(m, logits[k]);
    float s = 0.f;
    for (int k = 0; k < NCLS; ++k) s += expf(logits[k] - m);
    red[0] = m;
    red[1] = logf(s);
  }
  __syncthreads();
  if (t < NCLS) out[i * NCLS + t] = logits[t] - red[0] - red[1];
}

extern "C" void kernel_launch(void* const* d_in, const int* in_sizes, int n_in,
                              void* d_out, int out_size, void* d_ws, size_t ws_size,
                              hipStream_t stream) {
  const float* x = (const float*)d_in[0];
  const int* edge_index = (const int*)d_in[1];
  const int* batch = (const int*)d_in[2];
  const float* W1 = (const float*)d_in[3];
  const float* b1 = (const float*)d_in[4];
  const float* W2 = (const float*)d_in[5];
  const float* b2 = (const float*)d_in[6];
  const float* Wl1 = (const float*)d_in[7];
  const float* bl1 = (const float*)d_in[8];
  const float* Wl2 = (const float*)d_in[9];
  const float* bl2 = (const float*)d_in[10];
  float* out = (float*)d_out;

  const int N = in_sizes[0] / INC;     // 50000
  const int E = in_sizes[1] / 2;       // 1600000
  const int* erow = edge_index;
  const int* ecol = edge_index + E;

  char* p = (char*)d_ws;
  auto alloc = [&](size_t bytes) {
    void* r = (void*)p;
    p += (bytes + 255) & ~(size_t)255;
    return r;
  };
  int* deg = (int*)alloc((size_t)N * 4);
  float* dis = (float*)alloc((size_t)N * 4);
  int* offsets = (int*)alloc((size_t)(N + 1) * 4);
  int* rows_csr = (int*)alloc((size_t)E * 4);
  unsigned* part = (unsigned*)alloc((size_t)E * 4);
  int* hist = (int*)alloc((size_t)(NB * NBLK) * 4);
  int* histBase = (int*)alloc((size_t)(NB * NBLK + 1) * 4);
  float* gsum = (float*)alloc((size_t)NG * HIDC * 4);
  int* gstart = (int*)alloc((size_t)(NG + 1) * 4);
  int* blockTotals = (int*)alloc((size_t)256 * 4);
  ushort* W1T = (ushort*)alloc((size_t)INC * HIDC * 2);
  ushort* W2T = (ushort*)alloc((size_t)HIDC * HIDC * 2);
  unsigned* x_cb = (unsigned*)alloc((size_t)N * INC * 2);      // 12.8 MB [4][N][16u]
  unsigned* agg1_cb = (unsigned*)alloc((size_t)N * INC * 2);   // 12.8 MB [4][N][16u]
  unsigned* h1_cb = (unsigned*)alloc((size_t)N * HIDC * 2);    // 25.6 MB [8][N][16u]
  unsigned* agg2_cb = (unsigned*)alloc((size_t)N * HIDC * 2);  // 25.6 MB [8][N][16u]
  ushort* h2 = (ushort*)x_cb;  // reuse x_cb+agg1_cb (dead after GEMM1): 25.6 MB row-major

  hipMemsetAsync(gsum, 0, (size_t)NG * HIDC * 4, stream);

  // bucketed CSR build
  const int chunk = (E + NBLK - 1) / NBLK;
  edge_hist<<<NBLK, 256, 0, stream>>>(ecol, hist, E, chunk);
  {
    const int nh = NB * NBLK;
    const int nbh = (nh + SCAN_VPB - 1) / SCAN_VPB;
    scanA<<<nbh, SCAN_T, 0, stream>>>(hist, histBase, blockTotals, nh);
    scanB<<<1, 64, 0, stream>>>(blockTotals, nbh);
    scanC<<<(nh + 255) / 256, 256, 0, stream>>>(histBase, blockTotals, nh);
  }
  edge_partition<<<NBLK, 256, 0, stream>>>(erow, ecol, histBase, part, E, chunk);
  bucket_deg_dis<<<NB, 256, 0, stream>>>(part, histBase, deg, dis, N);
  {
    const int nb = (N + SCAN_VPB - 1) / SCAN_VPB;
    scanA<<<nb, SCAN_T, 0, stream>>>(deg, offsets, blockTotals, N);
    scanB<<<1, 64, 0, stream>>>(blockTotals, nb);
    scanC<<<(N + 255) / 256, 256, 0, stream>>>(offsets, blockTotals, N);
  }
  bucket_csr<<<NB, 256, 0, stream>>>(part, histBase, offsets, rows_csr, N);

  // casts
  cast_x_cb<<<(N * 64 + 255) / 256, 256, 0, stream>>>(x, x_cb, N);
  {
    int tot = INC * HIDC + HIDC * HIDC;
    transpose_cast2<<<(tot + 255) / 256, 256, 0, stream>>>(W1, W1T, W2, W2T);
  }

  // layer 1: cb-blocked aggregate (4 slices), then GEMM(128->256) -> h1 in cb layout
  {
    dim3 agrid((N + 3) / 4, INC / 32);
    aggregate_cb<<<agrid, 256, 0, stream>>>(x_cb, dis, offsets, rows_csr, agg1_cb, N);
  }
  {
    dim3 grid((N + 127) / 128, HIDC / 128);
    gemm_mfma<INC, true><<<grid, 256, 0, stream>>>(
        (const ushort*)agg1_cb, W1T, b1, (ushort*)h1_cb, N);
  }
  // layer 2: cb-blocked aggregate (8 slices), then GEMM(256->256) -> h2 row-major
  {
    dim3 agrid((N + 3) / 4, HIDC / 32);
    aggregate_cb<<<agrid, 256, 0, stream>>>(h1_cb, dis, offsets, rows_csr, agg2_cb, N);
  }
  {
    dim3 grid((N + 127) / 128, HIDC / 128);
    gemm_mfma<HIDC, false><<<grid, 256, 0, stream>>>(
        (const ushort*)agg2_cb, W2T, b2, h2, N);
  }
  // pool + MLP
  find_bounds<<<(N + 255) / 256, 256, 0, stream>>>(batch, gstart, N);
  {
    dim3 pgrid(NG, POOL_SPLIT);
    pool_range_bf16<<<pgrid, HIDC, 0, stream>>>(h2, gstart, gsum);
  }
  mlp_kernel<<<NG, 64, 0, stream>>>(gsum, gstart, Wl1, bl1, Wl2, bl2, out);
}

// Round 7
// 484.251 us; speedup vs baseline: 1.6795x; 1.6795x over previous
//
#include <hip/hip_runtime.h>
#include <hip/hip_bf16.h>
#include <math.h>

#define NN 50000
#define NG 128
#define INC 128
#define HIDC 256
#define NCLS 10

#define NBLK 256   // partition chunks
#define BSH 8      // bucket = col >> 8
#define NB 196     // ceil(50000/256) buckets

typedef __attribute__((ext_vector_type(8))) short s8_t;    // 8 bf16 (4 VGPR)
typedef __attribute__((ext_vector_type(4))) float f4_t;    // 4 f32

__device__ inline f4_t mfma16(s8_t a, s8_t b, f4_t c) {
  return __builtin_amdgcn_mfma_f32_16x16x32_bf16(a, b, c, 0, 0, 0);
}

__device__ inline float bf2f(ushort u) {
  union { unsigned int i; float f; } c; c.i = ((unsigned int)u) << 16; return c.f;
}
__device__ inline ushort f2bf(float f) {
  __hip_bfloat16 h = __float2bfloat16(f);
  return *(ushort*)&h;
}
__device__ inline unsigned packbf(float a, float b) {
  return (unsigned)f2bf(a) | ((unsigned)f2bf(b) << 16);
}

__device__ inline void gload_lds16(const void* g, void* l) {
  __builtin_amdgcn_global_load_lds(
      (const __attribute__((address_space(1))) unsigned int*)g,
      (__attribute__((address_space(3))) unsigned int*)l, 16, 0, 0);
}

// ---------------- bucketed edge partition ----------------
__global__ __launch_bounds__(256) void edge_hist(const int* __restrict__ ecol,
                                                 int* __restrict__ hist, int E, int chunk) {
  __shared__ int h[NB];
  int blk = blockIdx.x;
  for (int i = threadIdx.x; i < NB; i += 256) h[i] = 0;
  __syncthreads();
  int e0 = blk * chunk, e1 = min(e0 + chunk, E);
  for (int e = e0 + threadIdx.x; e < e1; e += 256)
    atomicAdd(&h[ecol[e] >> BSH], 1);
  __syncthreads();
  for (int i = threadIdx.x; i < NB; i += 256) hist[i * NBLK + blk] = h[i];
}

// part entry: (row << 8) | (col & 255)
__global__ __launch_bounds__(256) void edge_partition(const int* __restrict__ erow,
                                                      const int* __restrict__ ecol,
                                                      const int* __restrict__ histBase,
                                                      unsigned* __restrict__ part,
                                                      int E, int chunk) {
  __shared__ int cur[NB];
  int blk = blockIdx.x;
  for (int i = threadIdx.x; i < NB; i += 256) cur[i] = histBase[i * NBLK + blk];
  __syncthreads();
  int e0 = blk * chunk, e1 = min(e0 + chunk, E);
  for (int e = e0 + threadIdx.x; e < e1; e += 256) {
    int c = ecol[e];
    int b = c >> BSH;
    int pos = atomicAdd(&cur[b], 1);
    part[pos] = ((unsigned)erow[e] << 8) | (unsigned)(c & 255);
  }
}

__global__ __launch_bounds__(256) void bucket_deg_dis(const unsigned* __restrict__ part,
                                                      const int* __restrict__ histBase,
                                                      int* __restrict__ deg,
                                                      float* __restrict__ dis, int N) {
  __shared__ int cnt[256];
  int b = blockIdx.x;
  cnt[threadIdx.x] = 0;
  __syncthreads();
  int s0 = histBase[b * NBLK];
  int s1 = histBase[(b + 1) * NBLK];
  for (int e = s0 + threadIdx.x; e < s1; e += 256)
    atomicAdd(&cnt[part[e] & 255], 1);
  __syncthreads();
  int node = (b << BSH) + threadIdx.x;
  if (node < N) {
    int d = cnt[threadIdx.x];
    deg[node] = d;
    dis[node] = rsqrtf((float)d + 1.0f);
  }
}

__global__ __launch_bounds__(256) void bucket_csr(const unsigned* __restrict__ part,
                                                  const int* __restrict__ histBase,
                                                  const int* __restrict__ offsets,
                                                  int* __restrict__ rows_csr, int N) {
  __shared__ int cur[256];
  int b = blockIdx.x;
  int node = (b << BSH) + threadIdx.x;
  cur[threadIdx.x] = (node < N) ? offsets[node] : 0;
  __syncthreads();
  int s0 = histBase[b * NBLK];
  int s1 = histBase[(b + 1) * NBLK];
  for (int e = s0 + threadIdx.x; e < s1; e += 256) {
    unsigned pv = part[e];
    int pos = atomicAdd(&cur[pv & 255], 1);
    rows_csr[pos] = (int)(pv >> 8);
  }
}

// ---------------- multi-block exclusive scan ----------------
#define SCAN_T 256
#define SCAN_V 8
#define SCAN_VPB (SCAN_T * SCAN_V)  // 2048

__global__ __launch_bounds__(SCAN_T) void scanA(const int* __restrict__ deg,
                                                int* __restrict__ offsets,
                                                int* __restrict__ blockTotals, int n) {
  __shared__ int sm[SCAN_T];
  int b = blockIdx.x;
  int t = threadIdx.x;
  int base = b * SCAN_VPB + t * SCAN_V;
  int v[SCAN_V];
  int run = 0;
  #pragma unroll
  for (int j = 0; j < SCAN_V; ++j) {
    int idx = base + j;
    int d = (idx < n) ? deg[idx] : 0;
    run += d;
    v[j] = run;
  }
  sm[t] = run;
  __syncthreads();
  #pragma unroll
  for (int off = 1; off < SCAN_T; off <<= 1) {
    int x = (t >= off) ? sm[t - off] : 0;
    __syncthreads();
    sm[t] += x;
    __syncthreads();
  }
  int excl = (t == 0) ? 0 : sm[t - 1];
  #pragma unroll
  for (int j = 0; j < SCAN_V; ++j) {
    int idx = base + j;
    if (idx < n) offsets[idx + 1] = v[j] + excl;
  }
  if (t == SCAN_T - 1) blockTotals[b] = sm[t];
}

__global__ void scanB(int* __restrict__ blockTotals, int nb) {
  if (threadIdx.x == 0 && blockIdx.x == 0) {
    int run = 0;
    for (int i = 0; i < nb; ++i) {
      int v = blockTotals[i];
      blockTotals[i] = run;
      run += v;
    }
  }
}

__global__ void scanC(int* __restrict__ offsets, const int* __restrict__ blockTotals, int n) {
  int stride = gridDim.x * blockDim.x;
  for (int i = blockIdx.x * blockDim.x + threadIdx.x; i < n; i += stride) {
    offsets[i + 1] += blockTotals[i / SCAN_VPB];
    if (i == 0) offsets[0] = 0;
  }
}

// ---------------- casts ----------------
// x [N][128] f32 -> x_cb [4][N][16 uints] (cb-blocked bf16 pairs)
__global__ void cast_x_cb(const float* __restrict__ x, unsigned* __restrict__ xcb, int N) {
  int t = blockIdx.x * 256 + threadIdx.x;
  if (t >= N * 64) return;
  int n = t >> 6, pp = t & 63;  // pp = channel pair 0..63
  float v0 = x[(long)n * 128 + 2 * pp];
  float v1 = x[(long)n * 128 + 2 * pp + 1];
  xcb[((long)(pp >> 4) * N + n) * 16 + (pp & 15)] = packbf(v0, v1);
}

// fused transpose+cast of W1 [128,256] and W2 [256,256]
__global__ void transpose_cast2(const float* __restrict__ W1, ushort* __restrict__ W1T,
                                const float* __restrict__ W2, ushort* __restrict__ W2T) {
  int idx = blockIdx.x * blockDim.x + threadIdx.x;
  if (idx < INC * HIDC) {
    int k = idx / HIDC, n = idx % HIDC;
    W1T[(long)n * INC + k] = f2bf(W1[idx]);
  }
  int i2 = idx - INC * HIDC;
  if (i2 >= 0 && i2 < HIDC * HIDC) {
    int k = i2 / HIDC, n = i2 % HIDC;
    W2T[(long)n * HIDC + k] = f2bf(W2[i2]);
  }
}

// ---------------- channel-blocked aggregation, one 16-lane group per node ----------------
// grid: (ceil(N/16), n_cb). Block 256 = 16 groups; group owns node's 32-ch slice,
// loops over ALL its edges with 4-wide manual unroll (4 indep gather chains/group).
__global__ __launch_bounds__(256) void aggregate_cb(
    const unsigned* __restrict__ xcb, const float* __restrict__ dis,
    const int* __restrict__ offsets, const int* __restrict__ rows_csr,
    unsigned* __restrict__ outcb, int N) {
  int node = blockIdx.x * 16 + (threadIdx.x >> 4);
  if (node >= N) return;
  int cl = threadIdx.x & 15;  // channel pair 0..15
  long cbN = (long)blockIdx.y * N;
  float di = dis[node];
  unsigned sv = xcb[(cbN + node) * 16 + cl];
  float a0 = bf2f((ushort)sv) * di * di;
  float a1 = bf2f((ushort)(sv >> 16)) * di * di;
  float b0 = 0.f, b1 = 0.f, c0 = 0.f, c1 = 0.f, d0 = 0.f, d1 = 0.f;
  int e = offsets[node], e1 = offsets[node + 1];
  for (; e + 3 < e1; e += 4) {
    int r0 = rows_csr[e], r1 = rows_csr[e + 1];
    int r2 = rows_csr[e + 2], r3 = rows_csr[e + 3];
    float s0 = dis[r0] * di, s1 = dis[r1] * di;
    float s2 = dis[r2] * di, s3 = dis[r3] * di;
    unsigned v0 = xcb[(cbN + r0) * 16 + cl];
    unsigned v1 = xcb[(cbN + r1) * 16 + cl];
    unsigned v2 = xcb[(cbN + r2) * 16 + cl];
    unsigned v3 = xcb[(cbN + r3) * 16 + cl];
    a0 = fmaf(bf2f((ushort)v0), s0, a0); a1 = fmaf(bf2f((ushort)(v0 >> 16)), s0, a1);
    b0 = fmaf(bf2f((ushort)v1), s1, b0); b1 = fmaf(bf2f((ushort)(v1 >> 16)), s1, b1);
    c0 = fmaf(bf2f((ushort)v2), s2, c0); c1 = fmaf(bf2f((ushort)(v2 >> 16)), s2, c1);
    d0 = fmaf(bf2f((ushort)v3), s3, d0); d1 = fmaf(bf2f((ushort)(v3 >> 16)), s3, d1);
  }
  for (; e < e1; ++e) {
    int r = rows_csr[e];
    float s = dis[r] * di;
    unsigned v = xcb[(cbN + r) * 16 + cl];
    a0 = fmaf(bf2f((ushort)v), s, a0); a1 = fmaf(bf2f((ushort)(v >> 16)), s, a1);
  }
  a0 += b0 + c0 + d0;
  a1 += b1 + c1 + d1;
  outcb[(cbN + node) * 16 + cl] = packbf(a0, a1);
}

// ---------------- MFMA GEMM (128x128 tile, grid.y=2) ----------------
// A in cb layout [K/32][M][32] bf16; WT row-major [256][K] bf16.
// OUTCB: write h in cb layout [8][M][32]; else row-major [M][256].
template <int K, bool OUTCB>
__global__ __launch_bounds__(256) void gemm_mfma(
    const ushort* __restrict__ A, const ushort* __restrict__ WT,
    const float* __restrict__ bias, ushort* __restrict__ outb, int M) {
  __shared__ ushort smem[16384];  // 32 KB: A at 0, B at 8192
  const int tid = threadIdx.x;
  const int lane = tid & 63;
  const int wave = tid >> 6;
  const int wm = wave >> 1, wn = wave & 1;
  const int m0 = blockIdx.x * 128;
  const int n0 = blockIdx.y * 128;

  f4_t acc[4][4] = {};

  for (int k0 = 0; k0 < K; k0 += 64) {
    __syncthreads();
    // stage A tile [128][64]: LDS slot s -> logical row=s>>3, chunk=(s&7)^(row&7)
    #pragma unroll
    for (int is = 0; is < 4; ++is) {
      int s = is * 256 + tid;
      int row = s >> 3;
      int ch = (s & 7) ^ (row & 7);
      int k = k0 + ch * 8;
      long grow = m0 + row; if (grow > M - 1) grow = M - 1;
      const ushort* g = A + ((long)(k >> 5) * M + grow) * 32 + (k & 31);
      gload_lds16(g, &smem[(is * 256 + wave * 64) * 8]);
    }
    // stage B tile (WT rows n0..n0+127)
    #pragma unroll
    for (int is = 0; is < 4; ++is) {
      int s = is * 256 + tid;
      int row = s >> 3;
      int ch = (s & 7) ^ (row & 7);
      const ushort* g = WT + (long)(n0 + row) * K + k0 + ch * 8;
      gload_lds16(g, &smem[8192 + (is * 256 + wave * 64) * 8]);
    }
    asm volatile("s_waitcnt vmcnt(0)" ::: "memory");
    __syncthreads();
    #pragma unroll
    for (int ks = 0; ks < 2; ++ks) {
      s8_t af[4], bfr[4];
      #pragma unroll
      for (int mi = 0; mi < 4; ++mi) {
        int row = wm * 64 + mi * 16 + (lane & 15);
        int ch = (ks * 4 + (lane >> 4)) ^ (row & 7);
        af[mi] = *(const s8_t*)(&smem[row * 64 + ch * 8]);
      }
      #pragma unroll
      for (int ni = 0; ni < 4; ++ni) {
        int row = wn * 64 + ni * 16 + (lane & 15);
        int ch = (ks * 4 + (lane >> 4)) ^ (row & 7);
        bfr[ni] = *(const s8_t*)(&smem[8192 + row * 64 + ch * 8]);
      }
      #pragma unroll
      for (int mi = 0; mi < 4; ++mi)
        #pragma unroll
        for (int ni = 0; ni < 4; ++ni)
          acc[mi][ni] = mfma16(af[mi], bfr[ni], acc[mi][ni]);
    }
  }
  // epilogue: D col=lane&15, row=(lane>>4)*4+r
  #pragma unroll
  for (int ni = 0; ni < 4; ++ni) {
    int col = n0 + wn * 64 + ni * 16 + (lane & 15);
    float bb = bias[col];
    #pragma unroll
    for (int mi = 0; mi < 4; ++mi) {
      #pragma unroll
      for (int r = 0; r < 4; ++r) {
        int row = m0 + wm * 64 + mi * 16 + (lane >> 4) * 4 + r;
        if (row < M) {
          float v = fmaxf(acc[mi][ni][r] + bb, 0.0f);
          if (OUTCB)
            outb[((long)(col >> 5) * M + row) * 32 + (col & 31)] = f2bf(v);
          else
            outb[(long)row * HIDC + col] = f2bf(v);
        }
      }
    }
  }
}

// ---------------- pool via sorted-batch ranges ----------------
__global__ void find_bounds(const int* __restrict__ batch, int* __restrict__ gstart, int n) {
  int stride = gridDim.x * blockDim.x;
  for (int i = blockIdx.x * blockDim.x + threadIdx.x; i < n; i += stride) {
    int b = batch[i];
    if (i == 0) {
      for (int g = 0; g <= b; ++g) gstart[g] = 0;
    } else {
      int pb = batch[i - 1];
      if (pb != b)
        for (int g = pb + 1; g <= b; ++g) gstart[g] = i;
    }
    if (i == n - 1) {
      for (int g = b + 1; g <= NG; ++g) gstart[g] = n;
    }
  }
}

#define POOL_SPLIT 8
__global__ __launch_bounds__(HIDC) void pool_range_bf16(const ushort* __restrict__ h,
                                                        const int* __restrict__ gstart,
                                                        float* __restrict__ gsum) {
  int g = blockIdx.x;
  int s = blockIdx.y;
  int c = threadIdx.x;
  int s0 = gstart[g], s1 = gstart[g + 1];
  int len = s1 - s0;
  int chunk = (len + POOL_SPLIT - 1) / POOL_SPLIT;
  int i0 = s0 + s * chunk;
  int i1 = min(i0 + chunk, s1);
  float acc = 0.0f;
  for (int i = i0; i < i1; ++i) acc += bf2f(h[(long)i * HIDC + c]);
  if (i1 > i0) atomicAdd(&gsum[g * HIDC + c], acc);
}

// ---------------- final MLP + log_softmax ----------------
__global__ __launch_bounds__(64) void mlp_kernel(
    const float* __restrict__ gsum, const int* __restrict__ gstart,
    const float* __restrict__ Wl1, const float* __restrict__ bl1,
    const float* __restrict__ Wl2, const float* __restrict__ bl2,
    float* __restrict__ out) {
  __shared__ float g[HIDC];
  __shared__ float hid[64];
  __shared__ float logits[NCLS];
  __shared__ float red[2];
  int i = blockIdx.x;
  int t = threadIdx.x;
  int cnt = gstart[i + 1] - gstart[i];
  float inv = 1.0f / fmaxf((float)cnt, 1.0f);
  for (int c = t; c < HIDC; c += 64) g[c] = gsum[i * HIDC + c] * inv;
  __syncthreads();
  float acc = bl1[t];
  for (int c = 0; c < HIDC; ++c) acc = fmaf(g[c], Wl1[c * 64 + t], acc);
  hid[t] = fmaxf(acc, 0.0f);
  __syncthreads();
  if (t < NCLS) {
    float l = bl2[t];
    for (int c = 0; c < 64; ++c) l = fmaf(hid[c], Wl2[c * NCLS + t], l);
    logits[t] = l;
  }
  __syncthreads();
  if (t == 0) {
    float m = -1e30f;
    for (int k = 0; k < NCLS; ++k) m = fmaxf(m, logits[k]);
    float s = 0.f;
    for (int k = 0; k < NCLS; ++k) s += expf(logits[k] - m);
    red[0] = m;
    red[1] = logf(s);
  }
  __syncthreads();
  if (t < NCLS) out[i * NCLS + t] = logits[t] - red[0] - red[1];
}

extern "C" void kernel_launch(void* const* d_in, const int* in_sizes, int n_in,
                              void* d_out, int out_size, void* d_ws, size_t ws_size,
                              hipStream_t stream) {
  const float* x = (const float*)d_in[0];
  const int* edge_index = (const int*)d_in[1];
  const int* batch = (const int*)d_in[2];
  const float* W1 = (const float*)d_in[3];
  const float* b1 = (const float*)d_in[4];
  const float* W2 = (const float*)d_in[5];
  const float* b2 = (const float*)d_in[6];
  const float* Wl1 = (const float*)d_in[7];
  const float* bl1 = (const float*)d_in[8];
  const float* Wl2 = (const float*)d_in[9];
  const float* bl2 = (const float*)d_in[10];
  float* out = (float*)d_out;

  const int N = in_sizes[0] / INC;     // 50000
  const int E = in_sizes[1] / 2;       // 1600000
  const int* erow = edge_index;
  const int* ecol = edge_index + E;

  char* p = (char*)d_ws;
  auto alloc = [&](size_t bytes) {
    void* r = (void*)p;
    p += (bytes + 255) & ~(size_t)255;
    return r;
  };
  int* deg = (int*)alloc((size_t)N * 4);
  float* dis = (float*)alloc((size_t)N * 4);
  int* offsets = (int*)alloc((size_t)(N + 1) * 4);
  int* rows_csr = (int*)alloc((size_t)E * 4);
  unsigned* part = (unsigned*)alloc((size_t)E * 4);
  int* hist = (int*)alloc((size_t)(NB * NBLK) * 4);
  int* histBase = (int*)alloc((size_t)(NB * NBLK + 1) * 4);
  float* gsum = (float*)alloc((size_t)NG * HIDC * 4);
  int* gstart = (int*)alloc((size_t)(NG + 1) * 4);
  int* blockTotals = (int*)alloc((size_t)256 * 4);
  ushort* W1T = (ushort*)alloc((size_t)INC * HIDC * 2);
  ushort* W2T = (ushort*)alloc((size_t)HIDC * HIDC * 2);
  unsigned* x_cb = (unsigned*)alloc((size_t)N * INC * 2);      // 12.8 MB [4][N][16u]
  unsigned* agg1_cb = (unsigned*)alloc((size_t)N * INC * 2);   // 12.8 MB [4][N][16u]
  unsigned* h1_cb = (unsigned*)alloc((size_t)N * HIDC * 2);    // 25.6 MB [8][N][16u]
  unsigned* agg2_cb = (unsigned*)alloc((size_t)N * HIDC * 2);  // 25.6 MB [8][N][16u]
  ushort* h2 = (ushort*)x_cb;  // reuse x_cb+agg1_cb (dead after GEMM1): 25.6 MB row-major

  hipMemsetAsync(gsum, 0, (size_t)NG * HIDC * 4, stream);

  // bucketed CSR build
  const int chunk = (E + NBLK - 1) / NBLK;
  edge_hist<<<NBLK, 256, 0, stream>>>(ecol, hist, E, chunk);
  {
    const int nh = NB * NBLK;
    const int nbh = (nh + SCAN_VPB - 1) / SCAN_VPB;
    scanA<<<nbh, SCAN_T, 0, stream>>>(hist, histBase, blockTotals, nh);
    scanB<<<1, 64, 0, stream>>>(blockTotals, nbh);
    scanC<<<(nh + 255) / 256, 256, 0, stream>>>(histBase, blockTotals, nh);
  }
  edge_partition<<<NBLK, 256, 0, stream>>>(erow, ecol, histBase, part, E, chunk);
  bucket_deg_dis<<<NB, 256, 0, stream>>>(part, histBase, deg, dis, N);
  {
    const int nb = (N + SCAN_VPB - 1) / SCAN_VPB;
    scanA<<<nb, SCAN_T, 0, stream>>>(deg, offsets, blockTotals, N);
    scanB<<<1, 64, 0, stream>>>(blockTotals, nb);
    scanC<<<(N + 255) / 256, 256, 0, stream>>>(offsets, blockTotals, N);
  }
  bucket_csr<<<NB, 256, 0, stream>>>(part, histBase, offsets, rows_csr, N);

  // casts
  cast_x_cb<<<(N * 64 + 255) / 256, 256, 0, stream>>>(x, x_cb, N);
  {
    int tot = INC * HIDC + HIDC * HIDC;
    transpose_cast2<<<(tot + 255) / 256, 256, 0, stream>>>(W1, W1T, W2, W2T);
  }

  // layer 1: cb-blocked aggregate (4 slices), then GEMM(128->256) -> h1 in cb layout
  {
    dim3 agrid((N + 15) / 16, INC / 32);
    aggregate_cb<<<agrid, 256, 0, stream>>>(x_cb, dis, offsets, rows_csr, agg1_cb, N);
  }
  {
    dim3 grid((N + 127) / 128, HIDC / 128);
    gemm_mfma<INC, true><<<grid, 256, 0, stream>>>(
        (const ushort*)agg1_cb, W1T, b1, (ushort*)h1_cb, N);
  }
  // layer 2: cb-blocked aggregate (8 slices), then GEMM(256->256) -> h2 row-major
  {
    dim3 agrid((N + 15) / 16, HIDC / 32);
    aggregate_cb<<<agrid, 256, 0, stream>>>(h1_cb, dis, offsets, rows_csr, agg2_cb, N);
  }
  {
    dim3 grid((N + 127) / 128, HIDC / 128);
    gemm_mfma<HIDC, false><<<grid, 256, 0, stream>>>(
        (const ushort*)agg2_cb, W2T, b2, h2, N);
  }
  // pool + MLP
  find_bounds<<<(N + 255) / 256, 256, 0, stream>>>(batch, gstart, N);
  {
    dim3 pgrid(NG, POOL_SPLIT);
    pool_range_bf16<<<pgrid, HIDC, 0, stream>>>(h2, gstart, gsum);
  }
  mlp_kernel<<<NG, 64, 0, stream>>>(gsum, gstart, Wl1, bl1, Wl2, bl2, out);
}

// Round 9
// 425.756 us; speedup vs baseline: 1.9103x; 1.1374x over previous
//
#include <hip/hip_runtime.h>
#include <hip/hip_bf16.h>
#include <math.h>

#define NN 50000
#define NG 128
#define INC 128
#define HIDC 256
#define NCLS 10

#define NBLK 256   // partition chunks
#define BSH 8      // bucket = col >> 8
#define NB 196     // ceil(50000/256) buckets

typedef __attribute__((ext_vector_type(8))) short s8_t;    // 8 bf16 (4 VGPR)
typedef __attribute__((ext_vector_type(4))) float f4_t;    // 4 f32

__device__ inline f4_t mfma16(s8_t a, s8_t b, f4_t c) {
  return __builtin_amdgcn_mfma_f32_16x16x32_bf16(a, b, c, 0, 0, 0);
}

__device__ inline float bf2f(ushort u) {
  union { unsigned int i; float f; } c; c.i = ((unsigned int)u) << 16; return c.f;
}
__device__ inline ushort f2bf(float f) {
  __hip_bfloat16 h = __float2bfloat16(f);
  return *(ushort*)&h;
}
__device__ inline unsigned packbf(float a, float b) {
  return (unsigned)f2bf(a) | ((unsigned)f2bf(b) << 16);
}
__device__ inline ushort f2h(float f) {
  _Float16 h = (_Float16)f; return *(ushort*)&h;
}
__device__ inline float h2f(ushort u) {
  _Float16 h = *(_Float16*)&u; return (float)h;
}

__device__ inline void gload_lds16(const void* g, void* l) {
  __builtin_amdgcn_global_load_lds(
      (const __attribute__((address_space(1))) unsigned int*)g,
      (__attribute__((address_space(3))) unsigned int*)l, 16, 0, 0);
}

// ---------------- bucketed edge partition ----------------
__global__ __launch_bounds__(256) void edge_hist(const int* __restrict__ ecol,
                                                 int* __restrict__ hist, int E, int chunk) {
  __shared__ int h[NB];
  int blk = blockIdx.x;
  for (int i = threadIdx.x; i < NB; i += 256) h[i] = 0;
  __syncthreads();
  int e0 = blk * chunk, e1 = min(e0 + chunk, E);
  for (int e = e0 + threadIdx.x; e < e1; e += 256)
    atomicAdd(&h[ecol[e] >> BSH], 1);
  __syncthreads();
  for (int i = threadIdx.x; i < NB; i += 256) hist[i * NBLK + blk] = h[i];
}

// part entry: (row << 8) | (col & 255)
__global__ __launch_bounds__(256) void edge_partition(const int* __restrict__ erow,
                                                      const int* __restrict__ ecol,
                                                      const int* __restrict__ histBase,
                                                      unsigned* __restrict__ part,
                                                      int E, int chunk) {
  __shared__ int cur[NB];
  int blk = blockIdx.x;
  for (int i = threadIdx.x; i < NB; i += 256) cur[i] = histBase[i * NBLK + blk];
  __syncthreads();
  int e0 = blk * chunk, e1 = min(e0 + chunk, E);
  for (int e = e0 + threadIdx.x; e < e1; e += 256) {
    int c = ecol[e];
    int b = c >> BSH;
    int pos = atomicAdd(&cur[b], 1);
    part[pos] = ((unsigned)erow[e] << 8) | (unsigned)(c & 255);
  }
}

__global__ __launch_bounds__(256) void bucket_deg_dis(const unsigned* __restrict__ part,
                                                      const int* __restrict__ histBase,
                                                      int* __restrict__ deg,
                                                      float* __restrict__ dis, int N) {
  __shared__ int cnt[256];
  int b = blockIdx.x;
  cnt[threadIdx.x] = 0;
  __syncthreads();
  int s0 = histBase[b * NBLK];
  int s1 = histBase[(b + 1) * NBLK];
  for (int e = s0 + threadIdx.x; e < s1; e += 256)
    atomicAdd(&cnt[part[e] & 255], 1);
  __syncthreads();
  int node = (b << BSH) + threadIdx.x;
  if (node < N) {
    int d = cnt[threadIdx.x];
    deg[node] = d;
    dis[node] = rsqrtf((float)d + 1.0f);
  }
}

// writes packed edge: (src << 16) | fp16(dis[src]*dis[dst])
__global__ __launch_bounds__(256) void bucket_csr_ew(const unsigned* __restrict__ part,
                                                     const int* __restrict__ histBase,
                                                     const int* __restrict__ offsets,
                                                     const float* __restrict__ dis,
                                                     unsigned* __restrict__ ew, int N) {
  __shared__ int cur[256];
  __shared__ float sdis[256];
  int b = blockIdx.x;
  int node = (b << BSH) + threadIdx.x;
  cur[threadIdx.x] = (node < N) ? offsets[node] : 0;
  sdis[threadIdx.x] = (node < N) ? dis[node] : 0.0f;
  __syncthreads();
  int s0 = histBase[b * NBLK];
  int s1 = histBase[(b + 1) * NBLK];
  for (int e = s0 + threadIdx.x; e < s1; e += 256) {
    unsigned pv = part[e];
    int c = pv & 255;
    int r = (int)(pv >> 8);
    int pos = atomicAdd(&cur[c], 1);
    float w = dis[r] * sdis[c];
    ew[pos] = ((unsigned)r << 16) | (unsigned)f2h(w);
  }
}

// ---------------- multi-block exclusive scan ----------------
#define SCAN_T 256
#define SCAN_V 8
#define SCAN_VPB (SCAN_T * SCAN_V)  // 2048

__global__ __launch_bounds__(SCAN_T) void scanA(const int* __restrict__ deg,
                                                int* __restrict__ offsets,
                                                int* __restrict__ blockTotals, int n) {
  __shared__ int sm[SCAN_T];
  int b = blockIdx.x;
  int t = threadIdx.x;
  int base = b * SCAN_VPB + t * SCAN_V;
  int v[SCAN_V];
  int run = 0;
  #pragma unroll
  for (int j = 0; j < SCAN_V; ++j) {
    int idx = base + j;
    int d = (idx < n) ? deg[idx] : 0;
    run += d;
    v[j] = run;
  }
  sm[t] = run;
  __syncthreads();
  #pragma unroll
  for (int off = 1; off < SCAN_T; off <<= 1) {
    int x = (t >= off) ? sm[t - off] : 0;
    __syncthreads();
    sm[t] += x;
    __syncthreads();
  }
  int excl = (t == 0) ? 0 : sm[t - 1];
  #pragma unroll
  for (int j = 0; j < SCAN_V; ++j) {
    int idx = base + j;
    if (idx < n) offsets[idx + 1] = v[j] + excl;
  }
  if (t == SCAN_T - 1) blockTotals[b] = sm[t];
}

__global__ void scanB(int* __restrict__ blockTotals, int nb) {
  if (threadIdx.x == 0 && blockIdx.x == 0) {
    int run = 0;
    for (int i = 0; i < nb; ++i) {
      int v = blockTotals[i];
      blockTotals[i] = run;
      run += v;
    }
  }
}

__global__ void scanC(int* __restrict__ offsets, const int* __restrict__ blockTotals, int n) {
  int stride = gridDim.x * blockDim.x;
  for (int i = blockIdx.x * blockDim.x + threadIdx.x; i < n; i += stride) {
    offsets[i + 1] += blockTotals[i / SCAN_VPB];
    if (i == 0) offsets[0] = 0;
  }
}

// ---------------- casts ----------------
// x [N][128] f32 -> x_cb [4][N][16 uints] (cb-blocked bf16 pairs)
__global__ void cast_x_cb(const float* __restrict__ x, unsigned* __restrict__ xcb, int N) {
  int t = blockIdx.x * 256 + threadIdx.x;
  if (t >= N * 64) return;
  int n = t >> 6, pp = t & 63;  // pp = channel pair 0..63
  float v0 = x[(long)n * 128 + 2 * pp];
  float v1 = x[(long)n * 128 + 2 * pp + 1];
  xcb[((long)(pp >> 4) * N + n) * 16 + (pp & 15)] = packbf(v0, v1);
}

// fused transpose+cast of W1 [128,256] and W2 [256,256]
__global__ void transpose_cast2(const float* __restrict__ W1, ushort* __restrict__ W1T,
                                const float* __restrict__ W2, ushort* __restrict__ W2T) {
  int idx = blockIdx.x * blockDim.x + threadIdx.x;
  if (idx < INC * HIDC) {
    int k = idx / HIDC, n = idx % HIDC;
    W1T[(long)n * INC + k] = f2bf(W1[idx]);
  }
  int i2 = idx - INC * HIDC;
  if (i2 >= 0 && i2 < HIDC * HIDC) {
    int k = i2 / HIDC, n = i2 % HIDC;
    W2T[(long)n * HIDC + k] = f2bf(W2[i2]);
  }
}

// ---------------- channel-blocked aggregation, 8-lane group per node ----------------
// grid: (ceil(N/32), n_cb). Block 256 = 32 groups of 8 lanes; group owns one node's
// 32-ch slice (8 lanes x uint2 = 64B). Edge stream = packed (src<<16 | fp16 w).
// 4-wide manual unroll -> 4 indep gather chains per group, 8 edges per wave instr.
__global__ __launch_bounds__(256) void aggregate_cb(
    const uint2* __restrict__ xcb, const float* __restrict__ dis,
    const int* __restrict__ offsets, const unsigned* __restrict__ ew,
    uint2* __restrict__ outcb, int N) {
  int node = blockIdx.x * 32 + (threadIdx.x >> 3);
  if (node >= N) return;
  int cl = threadIdx.x & 7;  // uint2 index within row slice
  const uint2* xs = xcb + (long)blockIdx.y * N * 8;
  uint2* os = outcb + (long)blockIdx.y * N * 8;
  float di = dis[node];
  float dd = di * di;
  uint2 sv = xs[node * 8 + cl];
  float a0 = bf2f((ushort)sv.x) * dd;
  float a1 = bf2f((ushort)(sv.x >> 16)) * dd;
  float a2 = bf2f((ushort)sv.y) * dd;
  float a3 = bf2f((ushort)(sv.y >> 16)) * dd;
  float b0 = 0, b1 = 0, b2 = 0, b3 = 0;
  float c0 = 0, c1 = 0, c2 = 0, c3 = 0;
  float d0 = 0, d1 = 0, d2 = 0, d3 = 0;
  int e = offsets[node], eE = offsets[node + 1];
  for (; e + 3 < eE; e += 4) {
    unsigned p0 = ew[e], p1 = ew[e + 1], p2 = ew[e + 2], p3 = ew[e + 3];
    uint2 v0 = xs[(p0 >> 16) * 8 + cl];
    uint2 v1 = xs[(p1 >> 16) * 8 + cl];
    uint2 v2 = xs[(p2 >> 16) * 8 + cl];
    uint2 v3 = xs[(p3 >> 16) * 8 + cl];
    float w0 = h2f((ushort)p0), w1 = h2f((ushort)p1);
    float w2 = h2f((ushort)p2), w3 = h2f((ushort)p3);
    a0 = fmaf(bf2f((ushort)v0.x), w0, a0); a1 = fmaf(bf2f((ushort)(v0.x >> 16)), w0, a1);
    a2 = fmaf(bf2f((ushort)v0.y), w0, a2); a3 = fmaf(bf2f((ushort)(v0.y >> 16)), w0, a3);
    b0 = fmaf(bf2f((ushort)v1.x), w1, b0); b1 = fmaf(bf2f((ushort)(v1.x >> 16)), w1, b1);
    b2 = fmaf(bf2f((ushort)v1.y), w1, b2); b3 = fmaf(bf2f((ushort)(v1.y >> 16)), w1, b3);
    c0 = fmaf(bf2f((ushort)v2.x), w2, c0); c1 = fmaf(bf2f((ushort)(v2.x >> 16)), w2, c1);
    c2 = fmaf(bf2f((ushort)v2.y), w2, c2); c3 = fmaf(bf2f((ushort)(v2.y >> 16)), w2, c3);
    d0 = fmaf(bf2f((ushort)v3.x), w3, d0); d1 = fmaf(bf2f((ushort)(v3.x >> 16)), w3, d1);
    d2 = fmaf(bf2f((ushort)v3.y), w3, d2); d3 = fmaf(bf2f((ushort)(v3.y >> 16)), w3, d3);
  }
  for (; e < eE; ++e) {
    unsigned p0 = ew[e];
    uint2 v0 = xs[(p0 >> 16) * 8 + cl];
    float w0 = h2f((ushort)p0);
    a0 = fmaf(bf2f((ushort)v0.x), w0, a0); a1 = fmaf(bf2f((ushort)(v0.x >> 16)), w0, a1);
    a2 = fmaf(bf2f((ushort)v0.y), w0, a2); a3 = fmaf(bf2f((ushort)(v0.y >> 16)), w0, a3);
  }
  a0 += b0 + c0 + d0; a1 += b1 + c1 + d1;
  a2 += b2 + c2 + d2; a3 += b3 + c3 + d3;
  os[node * 8 + cl] = make_uint2(packbf(a0, a1), packbf(a2, a3));
}

// ---------------- MFMA GEMM (128x128 tile, grid.y=2) ----------------
// A in cb layout [K/32][M][32] bf16; WT row-major [256][K] bf16.
// OUTCB: write h in cb layout [8][M][32]; else row-major [M][256].
template <int K, bool OUTCB>
__global__ __launch_bounds__(256) void gemm_mfma(
    const ushort* __restrict__ A, const ushort* __restrict__ WT,
    const float* __restrict__ bias, ushort* __restrict__ outb, int M) {
  __shared__ ushort smem[16384];  // 32 KB: A at 0, B at 8192
  const int tid = threadIdx.x;
  const int lane = tid & 63;
  const int wave = tid >> 6;
  const int wm = wave >> 1, wn = wave & 1;
  const int m0 = blockIdx.x * 128;
  const int n0 = blockIdx.y * 128;

  f4_t acc[4][4] = {};

  for (int k0 = 0; k0 < K; k0 += 64) {
    __syncthreads();
    // stage A tile [128][64]: LDS slot s -> logical row=s>>3, chunk=(s&7)^(row&7)
    #pragma unroll
    for (int is = 0; is < 4; ++is) {
      int s = is * 256 + tid;
      int row = s >> 3;
      int ch = (s & 7) ^ (row & 7);
      int k = k0 + ch * 8;
      long grow = m0 + row; if (grow > M - 1) grow = M - 1;
      const ushort* g = A + ((long)(k >> 5) * M + grow) * 32 + (k & 31);
      gload_lds16(g, &smem[(is * 256 + wave * 64) * 8]);
    }
    // stage B tile (WT rows n0..n0+127)
    #pragma unroll
    for (int is = 0; is < 4; ++is) {
      int s = is * 256 + tid;
      int row = s >> 3;
      int ch = (s & 7) ^ (row & 7);
      const ushort* g = WT + (long)(n0 + row) * K + k0 + ch * 8;
      gload_lds16(g, &smem[8192 + (is * 256 + wave * 64) * 8]);
    }
    asm volatile("s_waitcnt vmcnt(0)" ::: "memory");
    __syncthreads();
    #pragma unroll
    for (int ks = 0; ks < 2; ++ks) {
      s8_t af[4], bfr[4];
      #pragma unroll
      for (int mi = 0; mi < 4; ++mi) {
        int row = wm * 64 + mi * 16 + (lane & 15);
        int ch = (ks * 4 + (lane >> 4)) ^ (row & 7);
        af[mi] = *(const s8_t*)(&smem[row * 64 + ch * 8]);
      }
      #pragma unroll
      for (int ni = 0; ni < 4; ++ni) {
        int row = wn * 64 + ni * 16 + (lane & 15);
        int ch = (ks * 4 + (lane >> 4)) ^ (row & 7);
        bfr[ni] = *(const s8_t*)(&smem[8192 + row * 64 + ch * 8]);
      }
      #pragma unroll
      for (int mi = 0; mi < 4; ++mi)
        #pragma unroll
        for (int ni = 0; ni < 4; ++ni)
          acc[mi][ni] = mfma16(af[mi], bfr[ni], acc[mi][ni]);
    }
  }
  // epilogue: D col=lane&15, row=(lane>>4)*4+r
  #pragma unroll
  for (int ni = 0; ni < 4; ++ni) {
    int col = n0 + wn * 64 + ni * 16 + (lane & 15);
    float bb = bias[col];
    #pragma unroll
    for (int mi = 0; mi < 4; ++mi) {
      #pragma unroll
      for (int r = 0; r < 4; ++r) {
        int row = m0 + wm * 64 + mi * 16 + (lane >> 4) * 4 + r;
        if (row < M) {
          float v = fmaxf(acc[mi][ni][r] + bb, 0.0f);
          if (OUTCB)
            outb[((long)(col >> 5) * M + row) * 32 + (col & 31)] = f2bf(v);
          else
            outb[(long)row * HIDC + col] = f2bf(v);
        }
      }
    }
  }
}

// ---------------- pool via sorted-batch ranges ----------------
__global__ void find_bounds(const int* __restrict__ batch, int* __restrict__ gstart, int n) {
  int stride = gridDim.x * blockDim.x;
  for (int i = blockIdx.x * blockDim.x + threadIdx.x; i < n; i += stride) {
    int b = batch[i];
    if (i == 0) {
      for (int g = 0; g <= b; ++g) gstart[g] = 0;
    } else {
      int pb = batch[i - 1];
      if (pb != b)
        for (int g = pb + 1; g <= b; ++g) gstart[g] = i;
    }
    if (i == n - 1) {
      for (int g = b + 1; g <= NG; ++g) gstart[g] = n;
    }
  }
}

#define POOL_SPLIT 8
__global__ __launch_bounds__(HIDC) void pool_range_bf16(const ushort* __restrict__ h,
                                                        const int* __restrict__ gstart,
                                                        float* __restrict__ gsum) {
  int g = blockIdx.x;
  int s = blockIdx.y;
  int c = threadIdx.x;
  int s0 = gstart[g], s1 = gstart[g + 1];
  int len = s1 - s0;
  int chunk = (len + POOL_SPLIT - 1) / POOL_SPLIT;
  int i0 = s0 + s * chunk;
  int i1 = min(i0 + chunk, s1);
  float acc = 0.0f;
  for (int i = i0; i < i1; ++i) acc += bf2f(h[(long)i * HIDC + c]);
  if (i1 > i0) atomicAdd(&gsum[g * HIDC + c], acc);
}

// ---------------- final MLP + log_softmax ----------------
__global__ __launch_bounds__(64) void mlp_kernel(
    const float* __restrict__ gsum, const int* __restrict__ gstart,
    const float* __restrict__ Wl1, const float* __restrict__ bl1,
    const float* __restrict__ Wl2, const float* __restrict__ bl2,
    float* __restrict__ out) {
  __shared__ float g[HIDC];
  __shared__ float hid[64];
  __shared__ float logits[NCLS];
  __shared__ float red[2];
  int i = blockIdx.x;
  int t = threadIdx.x;
  int cnt = gstart[i + 1] - gstart[i];
  float inv = 1.0f / fmaxf((float)cnt, 1.0f);
  for (int c = t; c < HIDC; c += 64) g[c] = gsum[i * HIDC + c] * inv;
  __syncthreads();
  float acc = bl1[t];
  for (int c = 0; c < HIDC; ++c) acc = fmaf(g[c], Wl1[c * 64 + t], acc);
  hid[t] = fmaxf(acc, 0.0f);
  __syncthreads();
  if (t < NCLS) {
    float l = bl2[t];
    for (int c = 0; c < 64; ++c) l = fmaf(hid[c], Wl2[c * NCLS + t], l);
    logits[t] = l;
  }
  __syncthreads();
  if (t == 0) {
    float m = -1e30f;
    for (int k = 0; k < NCLS; ++k) m = fmaxf(m, logits[k]);
    float s = 0.f;
    for (int k = 0; k < NCLS; ++k) s += expf(logits[k] - m);
    red[0] = m;
    red[1] = logf(s);
  }
  __syncthreads();
  if (t < NCLS) out[i * NCLS + t] = logits[t] - red[0] - red[1];
}

extern "C" void kernel_launch(void* const* d_in, const int* in_sizes, int n_in,
                              void* d_out, int out_size, void* d_ws, size_t ws_size,
                              hipStream_t stream) {
  const float* x = (const float*)d_in[0];
  const int* edge_index = (const int*)d_in[1];
  const int* batch = (const int*)d_in[2];
  const float* W1 = (const float*)d_in[3];
  const float* b1 = (const float*)d_in[4];
  const float* W2 = (const float*)d_in[5];
  const float* b2 = (const float*)d_in[6];
  const float* Wl1 = (const float*)d_in[7];
  const float* bl1 = (const float*)d_in[8];
  const float* Wl2 = (const float*)d_in[9];
  const float* bl2 = (const float*)d_in[10];
  float* out = (float*)d_out;

  const int N = in_sizes[0] / INC;     // 50000
  const int E = in_sizes[1] / 2;       // 1600000
  const int* erow = edge_index;
  const int* ecol = edge_index + E;

  char* p = (char*)d_ws;
  auto alloc = [&](size_t bytes) {
    void* r = (void*)p;
    p += (bytes + 255) & ~(size_t)255;
    return r;
  };
  int* deg = (int*)alloc((size_t)N * 4);
  float* dis = (float*)alloc((size_t)N * 4);
  int* offsets = (int*)alloc((size_t)(N + 1) * 4);
  unsigned* ew = (unsigned*)alloc((size_t)E * 4);
  unsigned* part = (unsigned*)alloc((size_t)E * 4);
  int* hist = (int*)alloc((size_t)(NB * NBLK) * 4);
  int* histBase = (int*)alloc((size_t)(NB * NBLK + 1) * 4);
  float* gsum = (float*)alloc((size_t)NG * HIDC * 4);
  int* gstart = (int*)alloc((size_t)(NG + 1) * 4);
  int* blockTotals = (int*)alloc((size_t)256 * 4);
  ushort* W1T = (ushort*)alloc((size_t)INC * HIDC * 2);
  ushort* W2T = (ushort*)alloc((size_t)HIDC * HIDC * 2);
  unsigned* x_cb = (unsigned*)alloc((size_t)N * INC * 2);      // 12.8 MB [4][N][16u]
  unsigned* agg1_cb = (unsigned*)alloc((size_t)N * INC * 2);   // 12.8 MB [4][N][16u]
  unsigned* h1_cb = (unsigned*)alloc((size_t)N * HIDC * 2);    // 25.6 MB [8][N][16u]
  unsigned* agg2_cb = (unsigned*)alloc((size_t)N * HIDC * 2);  // 25.6 MB [8][N][16u]
  ushort* h2 = (ushort*)x_cb;  // reuse x_cb+agg1_cb (dead after GEMM1): 25.6 MB row-major

  hipMemsetAsync(gsum, 0, (size_t)NG * HIDC * 4, stream);

  // bucketed CSR build
  const int chunk = (E + NBLK - 1) / NBLK;
  edge_hist<<<NBLK, 256, 0, stream>>>(ecol, hist, E, chunk);
  {
    const int nh = NB * NBLK;
    const int nbh = (nh + SCAN_VPB - 1) / SCAN_VPB;
    scanA<<<nbh, SCAN_T, 0, stream>>>(hist, histBase, blockTotals, nh);
    scanB<<<1, 64, 0, stream>>>(blockTotals, nbh);
    scanC<<<(nh + 255) / 256, 256, 0, stream>>>(histBase, blockTotals, nh);
  }
  edge_partition<<<NBLK, 256, 0, stream>>>(erow, ecol, histBase, part, E, chunk);
  bucket_deg_dis<<<NB, 256, 0, stream>>>(part, histBase, deg, dis, N);
  {
    const int nb = (N + SCAN_VPB - 1) / SCAN_VPB;
    scanA<<<nb, SCAN_T, 0, stream>>>(deg, offsets, blockTotals, N);
    scanB<<<1, 64, 0, stream>>>(blockTotals, nb);
    scanC<<<(N + 255) / 256, 256, 0, stream>>>(offsets, blockTotals, N);
  }
  bucket_csr_ew<<<NB, 256, 0, stream>>>(part, histBase, offsets, dis, ew, N);

  // casts
  cast_x_cb<<<(N * 64 + 255) / 256, 256, 0, stream>>>(x, x_cb, N);
  {
    int tot = INC * HIDC + HIDC * HIDC;
    transpose_cast2<<<(tot + 255) / 256, 256, 0, stream>>>(W1, W1T, W2, W2T);
  }

  // layer 1: cb-blocked aggregate (4 slices), then GEMM(128->256) -> h1 in cb layout
  {
    dim3 agrid((N + 31) / 32, INC / 32);
    aggregate_cb<<<agrid, 256, 0, stream>>>(
        (const uint2*)x_cb, dis, offsets, ew, (uint2*)agg1_cb, N);
  }
  {
    dim3 grid((N + 127) / 128, HIDC / 128);
    gemm_mfma<INC, true><<<grid, 256, 0, stream>>>(
        (const ushort*)agg1_cb, W1T, b1, (ushort*)h1_cb, N);
  }
  // layer 2: cb-blocked aggregate (8 slices), then GEMM(256->256) -> h2 row-major
  {
    dim3 agrid((N + 31) / 32, HIDC / 32);
    aggregate_cb<<<agrid, 256, 0, stream>>>(
        (const uint2*)h1_cb, dis, offsets, ew, (uint2*)agg2_cb, N);
  }
  {
    dim3 grid((N + 127) / 128, HIDC / 128);
    gemm_mfma<HIDC, false><<<grid, 256, 0, stream>>>(
        (const ushort*)agg2_cb, W2T, b2, h2, N);
  }
  // pool + MLP
  find_bounds<<<(N + 255) / 256, 256, 0, stream>>>(batch, gstart, N);
  {
    dim3 pgrid(NG, POOL_SPLIT);
    pool_range_bf16<<<pgrid, HIDC, 0, stream>>>(h2, gstart, gsum);
  }
  mlp_kernel<<<NG, 64, 0, stream>>>(gsum, gstart, Wl1, bl1, Wl2, bl2, out);
}

// Round 10
// 405.392 us; speedup vs baseline: 2.0063x; 1.0502x over previous
//
#include <hip/hip_runtime.h>
#include <hip/hip_bf16.h>
#include <math.h>

#define NN 50000
#define NG 128
#define INC 128
#define HIDC 256
#define NCLS 10

#define NBLK 256   // partition chunks
#define BSH 8      // bucket = col >> 8
#define NB 196     // ceil(50000/256) buckets

typedef __attribute__((ext_vector_type(8))) short s8_t;    // 8 bf16 (4 VGPR)
typedef __attribute__((ext_vector_type(4))) float f4_t;    // 4 f32

__device__ inline f4_t mfma16(s8_t a, s8_t b, f4_t c) {
  return __builtin_amdgcn_mfma_f32_16x16x32_bf16(a, b, c, 0, 0, 0);
}

__device__ inline float bf2f(ushort u) {
  union { unsigned int i; float f; } c; c.i = ((unsigned int)u) << 16; return c.f;
}
__device__ inline ushort f2bf(float f) {
  __hip_bfloat16 h = __float2bfloat16(f);
  return *(ushort*)&h;
}
__device__ inline unsigned packbf(float a, float b) {
  return (unsigned)f2bf(a) | ((unsigned)f2bf(b) << 16);
}
__device__ inline ushort f2h(float f) {
  _Float16 h = (_Float16)f; return *(ushort*)&h;
}
__device__ inline float h2f(ushort u) {
  _Float16 h = *(_Float16*)&u; return (float)h;
}

__device__ inline void gload_lds16(const void* g, void* l) {
  __builtin_amdgcn_global_load_lds(
      (const __attribute__((address_space(1))) unsigned int*)g,
      (__attribute__((address_space(3))) unsigned int*)l, 16, 0, 0);
}

// ---------------- bucketed edge partition ----------------
__global__ __launch_bounds__(256) void edge_hist(const int* __restrict__ ecol,
                                                 int* __restrict__ hist, int E, int chunk) {
  __shared__ int h[NB];
  int blk = blockIdx.x;
  for (int i = threadIdx.x; i < NB; i += 256) h[i] = 0;
  __syncthreads();
  int e0 = blk * chunk, e1 = min(e0 + chunk, E);
  for (int e = e0 + threadIdx.x; e < e1; e += 256)
    atomicAdd(&h[ecol[e] >> BSH], 1);
  __syncthreads();
  for (int i = threadIdx.x; i < NB; i += 256) hist[i * NBLK + blk] = h[i];
}

// part entry: (row << 8) | (col & 255)
__global__ __launch_bounds__(256) void edge_partition(const int* __restrict__ erow,
                                                      const int* __restrict__ ecol,
                                                      const int* __restrict__ histBase,
                                                      unsigned* __restrict__ part,
                                                      int E, int chunk) {
  __shared__ int cur[NB];
  int blk = blockIdx.x;
  for (int i = threadIdx.x; i < NB; i += 256) cur[i] = histBase[i * NBLK + blk];
  __syncthreads();
  int e0 = blk * chunk, e1 = min(e0 + chunk, E);
  for (int e = e0 + threadIdx.x; e < e1; e += 256) {
    int c = ecol[e];
    int b = c >> BSH;
    int pos = atomicAdd(&cur[b], 1);
    part[pos] = ((unsigned)erow[e] << 8) | (unsigned)(c & 255);
  }
}

__global__ __launch_bounds__(256) void bucket_deg_dis(const unsigned* __restrict__ part,
                                                      const int* __restrict__ histBase,
                                                      int* __restrict__ deg,
                                                      float* __restrict__ dis, int N) {
  __shared__ int cnt[256];
  int b = blockIdx.x;
  cnt[threadIdx.x] = 0;
  __syncthreads();
  int s0 = histBase[b * NBLK];
  int s1 = histBase[(b + 1) * NBLK];
  for (int e = s0 + threadIdx.x; e < s1; e += 256)
    atomicAdd(&cnt[part[e] & 255], 1);
  __syncthreads();
  int node = (b << BSH) + threadIdx.x;
  if (node < N) {
    int d = cnt[threadIdx.x];
    deg[node] = d;
    dis[node] = rsqrtf((float)d + 1.0f);
  }
}

// writes packed edge: (src << 16) | fp16(dis[src]*dis[dst])
__global__ __launch_bounds__(256) void bucket_csr_ew(const unsigned* __restrict__ part,
                                                     const int* __restrict__ histBase,
                                                     const int* __restrict__ offsets,
                                                     const float* __restrict__ dis,
                                                     unsigned* __restrict__ ew, int N) {
  __shared__ int cur[256];
  __shared__ float sdis[256];
  int b = blockIdx.x;
  int node = (b << BSH) + threadIdx.x;
  cur[threadIdx.x] = (node < N) ? offsets[node] : 0;
  sdis[threadIdx.x] = (node < N) ? dis[node] : 0.0f;
  __syncthreads();
  int s0 = histBase[b * NBLK];
  int s1 = histBase[(b + 1) * NBLK];
  for (int e = s0 + threadIdx.x; e < s1; e += 256) {
    unsigned pv = part[e];
    int c = pv & 255;
    int r = (int)(pv >> 8);
    int pos = atomicAdd(&cur[c], 1);
    float w = dis[r] * sdis[c];
    ew[pos] = ((unsigned)r << 16) | (unsigned)f2h(w);
  }
}

// ---------------- multi-block exclusive scan ----------------
#define SCAN_T 256
#define SCAN_V 8
#define SCAN_VPB (SCAN_T * SCAN_V)  // 2048

__global__ __launch_bounds__(SCAN_T) void scanA(const int* __restrict__ deg,
                                                int* __restrict__ offsets,
                                                int* __restrict__ blockTotals, int n) {
  __shared__ int sm[SCAN_T];
  int b = blockIdx.x;
  int t = threadIdx.x;
  int base = b * SCAN_VPB + t * SCAN_V;
  int v[SCAN_V];
  int run = 0;
  #pragma unroll
  for (int j = 0; j < SCAN_V; ++j) {
    int idx = base + j;
    int d = (idx < n) ? deg[idx] : 0;
    run += d;
    v[j] = run;
  }
  sm[t] = run;
  __syncthreads();
  #pragma unroll
  for (int off = 1; off < SCAN_T; off <<= 1) {
    int x = (t >= off) ? sm[t - off] : 0;
    __syncthreads();
    sm[t] += x;
    __syncthreads();
  }
  int excl = (t == 0) ? 0 : sm[t - 1];
  #pragma unroll
  for (int j = 0; j < SCAN_V; ++j) {
    int idx = base + j;
    if (idx < n) offsets[idx + 1] = v[j] + excl;
  }
  if (t == SCAN_T - 1) blockTotals[b] = sm[t];
}

__global__ void scanB(int* __restrict__ blockTotals, int nb) {
  if (threadIdx.x == 0 && blockIdx.x == 0) {
    int run = 0;
    for (int i = 0; i < nb; ++i) {
      int v = blockTotals[i];
      blockTotals[i] = run;
      run += v;
    }
  }
}

__global__ void scanC(int* __restrict__ offsets, const int* __restrict__ blockTotals, int n) {
  int stride = gridDim.x * blockDim.x;
  for (int i = blockIdx.x * blockDim.x + threadIdx.x; i < n; i += stride) {
    offsets[i + 1] += blockTotals[i / SCAN_VPB];
    if (i == 0) offsets[0] = 0;
  }
}

// ---------------- casts ----------------
// x [N][128] f32 -> x_cb [4][N][16 uints] (cb-blocked bf16 pairs)
__global__ void cast_x_cb(const float* __restrict__ x, unsigned* __restrict__ xcb, int N) {
  int t = blockIdx.x * 256 + threadIdx.x;
  if (t >= N * 64) return;
  int n = t >> 6, pp = t & 63;  // pp = channel pair 0..63
  float v0 = x[(long)n * 128 + 2 * pp];
  float v1 = x[(long)n * 128 + 2 * pp + 1];
  xcb[((long)(pp >> 4) * N + n) * 16 + (pp & 15)] = packbf(v0, v1);
}

// fused transpose+cast of W1 [128,256] and W2 [256,256]
__global__ void transpose_cast2(const float* __restrict__ W1, ushort* __restrict__ W1T,
                                const float* __restrict__ W2, ushort* __restrict__ W2T) {
  int idx = blockIdx.x * blockDim.x + threadIdx.x;
  if (idx < INC * HIDC) {
    int k = idx / HIDC, n = idx % HIDC;
    W1T[(long)n * INC + k] = f2bf(W1[idx]);
  }
  int i2 = idx - INC * HIDC;
  if (i2 >= 0 && i2 < HIDC * HIDC) {
    int k = i2 / HIDC, n = i2 % HIDC;
    W2T[(long)n * HIDC + k] = f2bf(W2[i2]);
  }
}

// ---------------- channel-blocked aggregation, XCD-pinned slices ----------------
// 1-D grid = nodeblocks << SSH. slice = blk & ((1<<SSH)-1) -> maps to a fixed XCD
// (dispatch round-robins blockIdx % 8 across XCDs), so each XCD's L2 permanently
// holds its slice's 3.2 MB table. Block 256 thr = 32 groups of 8 lanes; group owns
// one node's 32-ch slice (8 x uint2 = 64B). Edge stream = packed (src<<16 | fp16 w).
template <int SSH>
__global__ __launch_bounds__(256) void aggregate_cb(
    const uint2* __restrict__ xcb, const float* __restrict__ dis,
    const int* __restrict__ offsets, const unsigned* __restrict__ ew,
    uint2* __restrict__ outcb, int N) {
  int blk = blockIdx.x;
  int slice = blk & ((1 << SSH) - 1);
  int node = (blk >> SSH) * 32 + (threadIdx.x >> 3);
  if (node >= N) return;
  int cl = threadIdx.x & 7;  // uint2 index within row slice
  const uint2* xs = xcb + (long)slice * N * 8;
  uint2* os = outcb + (long)slice * N * 8;
  float di = dis[node];
  float dd = di * di;
  uint2 sv = xs[node * 8 + cl];
  float a0 = bf2f((ushort)sv.x) * dd;
  float a1 = bf2f((ushort)(sv.x >> 16)) * dd;
  float a2 = bf2f((ushort)sv.y) * dd;
  float a3 = bf2f((ushort)(sv.y >> 16)) * dd;
  float b0 = 0, b1 = 0, b2 = 0, b3 = 0;
  float c0 = 0, c1 = 0, c2 = 0, c3 = 0;
  float d0 = 0, d1 = 0, d2 = 0, d3 = 0;
  int e = offsets[node], eE = offsets[node + 1];
  for (; e + 3 < eE; e += 4) {
    unsigned p0 = ew[e], p1 = ew[e + 1], p2 = ew[e + 2], p3 = ew[e + 3];
    uint2 v0 = xs[(p0 >> 16) * 8 + cl];
    uint2 v1 = xs[(p1 >> 16) * 8 + cl];
    uint2 v2 = xs[(p2 >> 16) * 8 + cl];
    uint2 v3 = xs[(p3 >> 16) * 8 + cl];
    float w0 = h2f((ushort)p0), w1 = h2f((ushort)p1);
    float w2 = h2f((ushort)p2), w3 = h2f((ushort)p3);
    a0 = fmaf(bf2f((ushort)v0.x), w0, a0); a1 = fmaf(bf2f((ushort)(v0.x >> 16)), w0, a1);
    a2 = fmaf(bf2f((ushort)v0.y), w0, a2); a3 = fmaf(bf2f((ushort)(v0.y >> 16)), w0, a3);
    b0 = fmaf(bf2f((ushort)v1.x), w1, b0); b1 = fmaf(bf2f((ushort)(v1.x >> 16)), w1, b1);
    b2 = fmaf(bf2f((ushort)v1.y), w1, b2); b3 = fmaf(bf2f((ushort)(v1.y >> 16)), w1, b3);
    c0 = fmaf(bf2f((ushort)v2.x), w2, c0); c1 = fmaf(bf2f((ushort)(v2.x >> 16)), w2, c1);
    c2 = fmaf(bf2f((ushort)v2.y), w2, c2); c3 = fmaf(bf2f((ushort)(v2.y >> 16)), w2, c3);
    d0 = fmaf(bf2f((ushort)v3.x), w3, d0); d1 = fmaf(bf2f((ushort)(v3.x >> 16)), w3, d1);
    d2 = fmaf(bf2f((ushort)v3.y), w3, d2); d3 = fmaf(bf2f((ushort)(v3.y >> 16)), w3, d3);
  }
  for (; e < eE; ++e) {
    unsigned p0 = ew[e];
    uint2 v0 = xs[(p0 >> 16) * 8 + cl];
    float w0 = h2f((ushort)p0);
    a0 = fmaf(bf2f((ushort)v0.x), w0, a0); a1 = fmaf(bf2f((ushort)(v0.x >> 16)), w0, a1);
    a2 = fmaf(bf2f((ushort)v0.y), w0, a2); a3 = fmaf(bf2f((ushort)(v0.y >> 16)), w0, a3);
  }
  a0 += b0 + c0 + d0; a1 += b1 + c1 + d1;
  a2 += b2 + c2 + d2; a3 += b3 + c3 + d3;
  os[node * 8 + cl] = make_uint2(packbf(a0, a1), packbf(a2, a3));
}

// ---------------- MFMA GEMM (128x128 tile, grid.y=2) ----------------
// A in cb layout [K/32][M][32] bf16; WT row-major [256][K] bf16.
// OUTCB: write h in cb layout [8][M][32]; else row-major [M][256].
template <int K, bool OUTCB>
__global__ __launch_bounds__(256) void gemm_mfma(
    const ushort* __restrict__ A, const ushort* __restrict__ WT,
    const float* __restrict__ bias, ushort* __restrict__ outb, int M) {
  __shared__ ushort smem[16384];  // 32 KB: A at 0, B at 8192
  const int tid = threadIdx.x;
  const int lane = tid & 63;
  const int wave = tid >> 6;
  const int wm = wave >> 1, wn = wave & 1;
  const int m0 = blockIdx.x * 128;
  const int n0 = blockIdx.y * 128;

  f4_t acc[4][4] = {};

  for (int k0 = 0; k0 < K; k0 += 64) {
    __syncthreads();
    // stage A tile [128][64]: LDS slot s -> logical row=s>>3, chunk=(s&7)^(row&7)
    #pragma unroll
    for (int is = 0; is < 4; ++is) {
      int s = is * 256 + tid;
      int row = s >> 3;
      int ch = (s & 7) ^ (row & 7);
      int k = k0 + ch * 8;
      long grow = m0 + row; if (grow > M - 1) grow = M - 1;
      const ushort* g = A + ((long)(k >> 5) * M + grow) * 32 + (k & 31);
      gload_lds16(g, &smem[(is * 256 + wave * 64) * 8]);
    }
    // stage B tile (WT rows n0..n0+127)
    #pragma unroll
    for (int is = 0; is < 4; ++is) {
      int s = is * 256 + tid;
      int row = s >> 3;
      int ch = (s & 7) ^ (row & 7);
      const ushort* g = WT + (long)(n0 + row) * K + k0 + ch * 8;
      gload_lds16(g, &smem[8192 + (is * 256 + wave * 64) * 8]);
    }
    asm volatile("s_waitcnt vmcnt(0)" ::: "memory");
    __syncthreads();
    #pragma unroll
    for (int ks = 0; ks < 2; ++ks) {
      s8_t af[4], bfr[4];
      #pragma unroll
      for (int mi = 0; mi < 4; ++mi) {
        int row = wm * 64 + mi * 16 + (lane & 15);
        int ch = (ks * 4 + (lane >> 4)) ^ (row & 7);
        af[mi] = *(const s8_t*)(&smem[row * 64 + ch * 8]);
      }
      #pragma unroll
      for (int ni = 0; ni < 4; ++ni) {
        int row = wn * 64 + ni * 16 + (lane & 15);
        int ch = (ks * 4 + (lane >> 4)) ^ (row & 7);
        bfr[ni] = *(const s8_t*)(&smem[8192 + row * 64 + ch * 8]);
      }
      #pragma unroll
      for (int mi = 0; mi < 4; ++mi)
        #pragma unroll
        for (int ni = 0; ni < 4; ++ni)
          acc[mi][ni] = mfma16(af[mi], bfr[ni], acc[mi][ni]);
    }
  }
  // epilogue: D col=lane&15, row=(lane>>4)*4+r
  #pragma unroll
  for (int ni = 0; ni < 4; ++ni) {
    int col = n0 + wn * 64 + ni * 16 + (lane & 15);
    float bb = bias[col];
    #pragma unroll
    for (int mi = 0; mi < 4; ++mi) {
      #pragma unroll
      for (int r = 0; r < 4; ++r) {
        int row = m0 + wm * 64 + mi * 16 + (lane >> 4) * 4 + r;
        if (row < M) {
          float v = fmaxf(acc[mi][ni][r] + bb, 0.0f);
          if (OUTCB)
            outb[((long)(col >> 5) * M + row) * 32 + (col & 31)] = f2bf(v);
          else
            outb[(long)row * HIDC + col] = f2bf(v);
        }
      }
    }
  }
}

// ---------------- pool via sorted-batch ranges ----------------
__global__ void find_bounds(const int* __restrict__ batch, int* __restrict__ gstart, int n) {
  int stride = gridDim.x * blockDim.x;
  for (int i = blockIdx.x * blockDim.x + threadIdx.x; i < n; i += stride) {
    int b = batch[i];
    if (i == 0) {
      for (int g = 0; g <= b; ++g) gstart[g] = 0;
    } else {
      int pb = batch[i - 1];
      if (pb != b)
        for (int g = pb + 1; g <= b; ++g) gstart[g] = i;
    }
    if (i == n - 1) {
      for (int g = b + 1; g <= NG; ++g) gstart[g] = n;
    }
  }
}

#define POOL_SPLIT 8
__global__ __launch_bounds__(HIDC) void pool_range_bf16(const ushort* __restrict__ h,
                                                        const int* __restrict__ gstart,
                                                        float* __restrict__ gsum) {
  int g = blockIdx.x;
  int s = blockIdx.y;
  int c = threadIdx.x;
  int s0 = gstart[g], s1 = gstart[g + 1];
  int len = s1 - s0;
  int chunk = (len + POOL_SPLIT - 1) / POOL_SPLIT;
  int i0 = s0 + s * chunk;
  int i1 = min(i0 + chunk, s1);
  float acc = 0.0f;
  for (int i = i0; i < i1; ++i) acc += bf2f(h[(long)i * HIDC + c]);
  if (i1 > i0) atomicAdd(&gsum[g * HIDC + c], acc);
}

// ---------------- final MLP + log_softmax ----------------
__global__ __launch_bounds__(64) void mlp_kernel(
    const float* __restrict__ gsum, const int* __restrict__ gstart,
    const float* __restrict__ Wl1, const float* __restrict__ bl1,
    const float* __restrict__ Wl2, const float* __restrict__ bl2,
    float* __restrict__ out) {
  __shared__ float g[HIDC];
  __shared__ float hid[64];
  __shared__ float logits[NCLS];
  __shared__ float red[2];
  int i = blockIdx.x;
  int t = threadIdx.x;
  int cnt = gstart[i + 1] - gstart[i];
  float inv = 1.0f / fmaxf((float)cnt, 1.0f);
  for (int c = t; c < HIDC; c += 64) g[c] = gsum[i * HIDC + c] * inv;
  __syncthreads();
  float acc = bl1[t];
  for (int c = 0; c < HIDC; ++c) acc = fmaf(g[c], Wl1[c * 64 + t], acc);
  hid[t] = fmaxf(acc, 0.0f);
  __syncthreads();
  if (t < NCLS) {
    float l = bl2[t];
    for (int c = 0; c < 64; ++c) l = fmaf(hid[c], Wl2[c * NCLS + t], l);
    logits[t] = l;
  }
  __syncthreads();
  if (t == 0) {
    float m = -1e30f;
    for (int k = 0; k < NCLS; ++k) m = fmaxf(m, logits[k]);
    float s = 0.f;
    for (int k = 0; k < NCLS; ++k) s += expf(logits[k] - m);
    red[0] = m;
    red[1] = logf(s);
  }
  __syncthreads();
  if (t < NCLS) out[i * NCLS + t] = logits[t] - red[0] - red[1];
}

extern "C" void kernel_launch(void* const* d_in, const int* in_sizes, int n_in,
                              void* d_out, int out_size, void* d_ws, size_t ws_size,
                              hipStream_t stream) {
  const float* x = (const float*)d_in[0];
  const int* edge_index = (const int*)d_in[1];
  const int* batch = (const int*)d_in[2];
  const float* W1 = (const float*)d_in[3];
  const float* b1 = (const float*)d_in[4];
  const float* W2 = (const float*)d_in[5];
  const float* b2 = (const float*)d_in[6];
  const float* Wl1 = (const float*)d_in[7];
  const float* bl1 = (const float*)d_in[8];
  const float* Wl2 = (const float*)d_in[9];
  const float* bl2 = (const float*)d_in[10];
  float* out = (float*)d_out;

  const int N = in_sizes[0] / INC;     // 50000
  const int E = in_sizes[1] / 2;       // 1600000
  const int* erow = edge_index;
  const int* ecol = edge_index + E;

  char* p = (char*)d_ws;
  auto alloc = [&](size_t bytes) {
    void* r = (void*)p;
    p += (bytes + 255) & ~(size_t)255;
    return r;
  };
  int* deg = (int*)alloc((size_t)N * 4);
  float* dis = (float*)alloc((size_t)N * 4);
  int* offsets = (int*)alloc((size_t)(N + 1) * 4);
  unsigned* ew = (unsigned*)alloc((size_t)E * 4);
  unsigned* part = (unsigned*)alloc((size_t)E * 4);
  int* hist = (int*)alloc((size_t)(NB * NBLK) * 4);
  int* histBase = (int*)alloc((size_t)(NB * NBLK + 1) * 4);
  float* gsum = (float*)alloc((size_t)NG * HIDC * 4);
  int* gstart = (int*)alloc((size_t)(NG + 1) * 4);
  int* blockTotals = (int*)alloc((size_t)256 * 4);
  ushort* W1T = (ushort*)alloc((size_t)INC * HIDC * 2);
  ushort* W2T = (ushort*)alloc((size_t)HIDC * HIDC * 2);
  unsigned* x_cb = (unsigned*)alloc((size_t)N * INC * 2);      // 12.8 MB [4][N][16u]
  unsigned* agg1_cb = (unsigned*)alloc((size_t)N * INC * 2);   // 12.8 MB [4][N][16u]
  unsigned* h1_cb = (unsigned*)alloc((size_t)N * HIDC * 2);    // 25.6 MB [8][N][16u]
  unsigned* agg2_cb = (unsigned*)alloc((size_t)N * HIDC * 2);  // 25.6 MB [8][N][16u]
  ushort* h2 = (ushort*)x_cb;  // reuse x_cb+agg1_cb (dead after GEMM1): 25.6 MB row-major

  hipMemsetAsync(gsum, 0, (size_t)NG * HIDC * 4, stream);

  // bucketed CSR build
  const int chunk = (E + NBLK - 1) / NBLK;
  edge_hist<<<NBLK, 256, 0, stream>>>(ecol, hist, E, chunk);
  {
    const int nh = NB * NBLK;
    const int nbh = (nh + SCAN_VPB - 1) / SCAN_VPB;
    scanA<<<nbh, SCAN_T, 0, stream>>>(hist, histBase, blockTotals, nh);
    scanB<<<1, 64, 0, stream>>>(blockTotals, nbh);
    scanC<<<(nh + 255) / 256, 256, 0, stream>>>(histBase, blockTotals, nh);
  }
  edge_partition<<<NBLK, 256, 0, stream>>>(erow, ecol, histBase, part, E, chunk);
  bucket_deg_dis<<<NB, 256, 0, stream>>>(part, histBase, deg, dis, N);
  {
    const int nb = (N + SCAN_VPB - 1) / SCAN_VPB;
    scanA<<<nb, SCAN_T, 0, stream>>>(deg, offsets, blockTotals, N);
    scanB<<<1, 64, 0, stream>>>(blockTotals, nb);
    scanC<<<(N + 255) / 256, 256, 0, stream>>>(offsets, blockTotals, N);
  }
  bucket_csr_ew<<<NB, 256, 0, stream>>>(part, histBase, offsets, dis, ew, N);

  // casts
  cast_x_cb<<<(N * 64 + 255) / 256, 256, 0, stream>>>(x, x_cb, N);
  {
    int tot = INC * HIDC + HIDC * HIDC;
    transpose_cast2<<<(tot + 255) / 256, 256, 0, stream>>>(W1, W1T, W2, W2T);
  }

  const int nodeblks = (N + 31) / 32;  // 1563

  // layer 1: XCD-pinned cb aggregate (4 slices in low bits), GEMM -> h1 cb layout
  aggregate_cb<2><<<nodeblks << 2, 256, 0, stream>>>(
      (const uint2*)x_cb, dis, offsets, ew, (uint2*)agg1_cb, N);
  {
    dim3 grid((N + 127) / 128, HIDC / 128);
    gemm_mfma<INC, true><<<grid, 256, 0, stream>>>(
        (const ushort*)agg1_cb, W1T, b1, (ushort*)h1_cb, N);
  }
  // layer 2: XCD-pinned cb aggregate (8 slices in low bits), GEMM -> h2 row-major
  aggregate_cb<3><<<nodeblks << 3, 256, 0, stream>>>(
      (const uint2*)h1_cb, dis, offsets, ew, (uint2*)agg2_cb, N);
  {
    dim3 grid((N + 127) / 128, HIDC / 128);
    gemm_mfma<HIDC, false><<<grid, 256, 0, stream>>>(
        (const ushort*)agg2_cb, W2T, b2, h2, N);
  }
  // pool + MLP
  find_bounds<<<(N + 255) / 256, 256, 0, stream>>>(batch, gstart, N);
  {
    dim3 pgrid(NG, POOL_SPLIT);
    pool_range_bf16<<<pgrid, HIDC, 0, stream>>>(h2, gstart, gsum);
  }
  mlp_kernel<<<NG, 64, 0, stream>>>(gsum, gstart, Wl1, bl1, Wl2, bl2, out);
}

// Round 11
// 402.123 us; speedup vs baseline: 2.0226x; 1.0081x over previous
//
#include <hip/hip_runtime.h>
#include <hip/hip_bf16.h>
#include <math.h>

#define NN 50000
#define NG 128
#define INC 128
#define HIDC 256
#define NCLS 10

#define NBLK 256   // partition chunks
#define BSH 8      // bucket = col >> 8
#define NB 196     // ceil(50000/256) buckets

typedef __attribute__((ext_vector_type(8))) short s8_t;    // 8 bf16 (4 VGPR)
typedef __attribute__((ext_vector_type(4))) float f4_t;    // 4 f32

__device__ inline f4_t mfma16(s8_t a, s8_t b, f4_t c) {
  return __builtin_amdgcn_mfma_f32_16x16x32_bf16(a, b, c, 0, 0, 0);
}

__device__ inline float bf2f(ushort u) {
  union { unsigned int i; float f; } c; c.i = ((unsigned int)u) << 16; return c.f;
}
__device__ inline ushort f2bf(float f) {
  __hip_bfloat16 h = __float2bfloat16(f);
  return *(ushort*)&h;
}
__device__ inline unsigned packbf(float a, float b) {
  return (unsigned)f2bf(a) | ((unsigned)f2bf(b) << 16);
}
__device__ inline ushort f2h(float f) {
  _Float16 h = (_Float16)f; return *(ushort*)&h;
}
__device__ inline float h2f(ushort u) {
  _Float16 h = *(_Float16*)&u; return (float)h;
}

__device__ inline void gload_lds16(const void* g, void* l) {
  __builtin_amdgcn_global_load_lds(
      (const __attribute__((address_space(1))) unsigned int*)g,
      (__attribute__((address_space(3))) unsigned int*)l, 16, 0, 0);
}

// ---------------- bucketed edge partition ----------------
__global__ __launch_bounds__(256) void edge_hist(const int* __restrict__ ecol,
                                                 int* __restrict__ hist, int E, int chunk) {
  __shared__ int h[NB];
  int blk = blockIdx.x;
  for (int i = threadIdx.x; i < NB; i += 256) h[i] = 0;
  __syncthreads();
  int e0 = blk * chunk, e1 = min(e0 + chunk, E);
  for (int e = e0 + threadIdx.x; e < e1; e += 256)
    atomicAdd(&h[ecol[e] >> BSH], 1);
  __syncthreads();
  for (int i = threadIdx.x; i < NB; i += 256) hist[i * NBLK + blk] = h[i];
}

// part entry: (row << 8) | (col & 255)
__global__ __launch_bounds__(256) void edge_partition(const int* __restrict__ erow,
                                                      const int* __restrict__ ecol,
                                                      const int* __restrict__ histBase,
                                                      unsigned* __restrict__ part,
                                                      int E, int chunk) {
  __shared__ int cur[NB];
  int blk = blockIdx.x;
  for (int i = threadIdx.x; i < NB; i += 256) cur[i] = histBase[i * NBLK + blk];
  __syncthreads();
  int e0 = blk * chunk, e1 = min(e0 + chunk, E);
  for (int e = e0 + threadIdx.x; e < e1; e += 256) {
    int c = ecol[e];
    int b = c >> BSH;
    int pos = atomicAdd(&cur[b], 1);
    part[pos] = ((unsigned)erow[e] << 8) | (unsigned)(c & 255);
  }
}

__global__ __launch_bounds__(256) void bucket_deg_dis(const unsigned* __restrict__ part,
                                                      const int* __restrict__ histBase,
                                                      int* __restrict__ deg,
                                                      float* __restrict__ dis, int N) {
  __shared__ int cnt[256];
  int b = blockIdx.x;
  cnt[threadIdx.x] = 0;
  __syncthreads();
  int s0 = histBase[b * NBLK];
  int s1 = histBase[(b + 1) * NBLK];
  for (int e = s0 + threadIdx.x; e < s1; e += 256)
    atomicAdd(&cnt[part[e] & 255], 1);
  __syncthreads();
  int node = (b << BSH) + threadIdx.x;
  if (node < N) {
    int d = cnt[threadIdx.x];
    deg[node] = d;
    dis[node] = rsqrtf((float)d + 1.0f);
  }
}

// writes packed edge: (src << 16) | fp16(dis[src]*dis[dst])
__global__ __launch_bounds__(256) void bucket_csr_ew(const unsigned* __restrict__ part,
                                                     const int* __restrict__ histBase,
                                                     const int* __restrict__ offsets,
                                                     const float* __restrict__ dis,
                                                     unsigned* __restrict__ ew, int N) {
  __shared__ int cur[256];
  __shared__ float sdis[256];
  int b = blockIdx.x;
  int node = (b << BSH) + threadIdx.x;
  cur[threadIdx.x] = (node < N) ? offsets[node] : 0;
  sdis[threadIdx.x] = (node < N) ? dis[node] : 0.0f;
  __syncthreads();
  int s0 = histBase[b * NBLK];
  int s1 = histBase[(b + 1) * NBLK];
  for (int e = s0 + threadIdx.x; e < s1; e += 256) {
    unsigned pv = part[e];
    int c = pv & 255;
    int r = (int)(pv >> 8);
    int pos = atomicAdd(&cur[c], 1);
    float w = dis[r] * sdis[c];
    ew[pos] = ((unsigned)r << 16) | (unsigned)f2h(w);
  }
}

// ---------------- multi-block exclusive scan ----------------
#define SCAN_T 256
#define SCAN_V 8
#define SCAN_VPB (SCAN_T * SCAN_V)  // 2048

__global__ __launch_bounds__(SCAN_T) void scanA(const int* __restrict__ deg,
                                                int* __restrict__ offsets,
                                                int* __restrict__ blockTotals, int n) {
  __shared__ int sm[SCAN_T];
  int b = blockIdx.x;
  int t = threadIdx.x;
  int base = b * SCAN_VPB + t * SCAN_V;
  int v[SCAN_V];
  int run = 0;
  #pragma unroll
  for (int j = 0; j < SCAN_V; ++j) {
    int idx = base + j;
    int d = (idx < n) ? deg[idx] : 0;
    run += d;
    v[j] = run;
  }
  sm[t] = run;
  __syncthreads();
  #pragma unroll
  for (int off = 1; off < SCAN_T; off <<= 1) {
    int x = (t >= off) ? sm[t - off] : 0;
    __syncthreads();
    sm[t] += x;
    __syncthreads();
  }
  int excl = (t == 0) ? 0 : sm[t - 1];
  #pragma unroll
  for (int j = 0; j < SCAN_V; ++j) {
    int idx = base + j;
    if (idx < n) offsets[idx + 1] = v[j] + excl;
  }
  if (t == SCAN_T - 1) blockTotals[b] = sm[t];
}

__global__ void scanB(int* __restrict__ blockTotals, int nb) {
  if (threadIdx.x == 0 && blockIdx.x == 0) {
    int run = 0;
    for (int i = 0; i < nb; ++i) {
      int v = blockTotals[i];
      blockTotals[i] = run;
      run += v;
    }
  }
}

__global__ void scanC(int* __restrict__ offsets, const int* __restrict__ blockTotals, int n) {
  int stride = gridDim.x * blockDim.x;
  for (int i = blockIdx.x * blockDim.x + threadIdx.x; i < n; i += stride) {
    offsets[i + 1] += blockTotals[i / SCAN_VPB];
    if (i == 0) offsets[0] = 0;
  }
}

// ---------------- casts ----------------
// x [N][128] f32 -> x_cb [4][N][16 uints] (cb-blocked bf16 pairs)
__global__ void cast_x_cb(const float* __restrict__ x, unsigned* __restrict__ xcb, int N) {
  int t = blockIdx.x * 256 + threadIdx.x;
  if (t >= N * 64) return;
  int n = t >> 6, pp = t & 63;  // pp = channel pair 0..63
  float v0 = x[(long)n * 128 + 2 * pp];
  float v1 = x[(long)n * 128 + 2 * pp + 1];
  xcb[((long)(pp >> 4) * N + n) * 16 + (pp & 15)] = packbf(v0, v1);
}

// fused transpose+cast of W1 [128,256] and W2 [256,256]
__global__ void transpose_cast2(const float* __restrict__ W1, ushort* __restrict__ W1T,
                                const float* __restrict__ W2, ushort* __restrict__ W2T) {
  int idx = blockIdx.x * blockDim.x + threadIdx.x;
  if (idx < INC * HIDC) {
    int k = idx / HIDC, n = idx % HIDC;
    W1T[(long)n * INC + k] = f2bf(W1[idx]);
  }
  int i2 = idx - INC * HIDC;
  if (i2 >= 0 && i2 < HIDC * HIDC) {
    int k = i2 / HIDC, n = i2 % HIDC;
    W2T[(long)n * HIDC + k] = f2bf(W2[i2]);
  }
}

// ---------------- channel-blocked aggregation, XCD-pinned slices, 8-deep ILP ----
// MODE 0 (layer 2, 8 slices): slice = blk&7, nodeblk = blk>>3.
// MODE 1 (layer 1, 4 slices): slice = (blk>>1)&3 (bits 2:1), sub = blk&1,
//   nodeblk = (blk>>3)*2 + sub  -> each XCD hosts exactly one 3.2 MB slice.
// Group = 8 lanes owns one node's 32-ch slice (8 x uint2 = 64B); 8 indep gather
// chains in flight per group.
template <int MODE>
__global__ __launch_bounds__(256) void aggregate_cb(
    const uint2* __restrict__ xcb, const float* __restrict__ dis,
    const int* __restrict__ offsets, const unsigned* __restrict__ ew,
    uint2* __restrict__ outcb, int N) {
  int blk = blockIdx.x;
  int slice, nb;
  if (MODE == 0) { slice = blk & 7; nb = blk >> 3; }
  else           { slice = (blk >> 1) & 3; nb = ((blk >> 3) << 1) | (blk & 1); }
  int node = nb * 32 + (threadIdx.x >> 3);
  if (node >= N) return;
  int cl = threadIdx.x & 7;  // uint2 index within row slice
  const uint2* xs = xcb + (long)slice * N * 8;
  uint2* os = outcb + (long)slice * N * 8;
  float di = dis[node];
  float dd = di * di;
  uint2 sv = xs[node * 8 + cl];
  float a0 = bf2f((ushort)sv.x) * dd;
  float a1 = bf2f((ushort)(sv.x >> 16)) * dd;
  float a2 = bf2f((ushort)sv.y) * dd;
  float a3 = bf2f((ushort)(sv.y >> 16)) * dd;
  float b0 = 0, b1 = 0, b2 = 0, b3 = 0;
  float c0 = 0, c1 = 0, c2 = 0, c3 = 0;
  float d0 = 0, d1 = 0, d2 = 0, d3 = 0;
  int e = offsets[node], eE = offsets[node + 1];
  for (; e + 7 < eE; e += 8) {
    unsigned p0 = ew[e],     p1 = ew[e + 1], p2 = ew[e + 2], p3 = ew[e + 3];
    unsigned p4 = ew[e + 4], p5 = ew[e + 5], p6 = ew[e + 6], p7 = ew[e + 7];
    uint2 v0 = xs[(p0 >> 16) * 8 + cl];
    uint2 v1 = xs[(p1 >> 16) * 8 + cl];
    uint2 v2 = xs[(p2 >> 16) * 8 + cl];
    uint2 v3 = xs[(p3 >> 16) * 8 + cl];
    uint2 v4 = xs[(p4 >> 16) * 8 + cl];
    uint2 v5 = xs[(p5 >> 16) * 8 + cl];
    uint2 v6 = xs[(p6 >> 16) * 8 + cl];
    uint2 v7 = xs[(p7 >> 16) * 8 + cl];
    float w0 = h2f((ushort)p0), w1 = h2f((ushort)p1);
    float w2 = h2f((ushort)p2), w3 = h2f((ushort)p3);
    float w4 = h2f((ushort)p4), w5 = h2f((ushort)p5);
    float w6 = h2f((ushort)p6), w7 = h2f((ushort)p7);
    a0 = fmaf(bf2f((ushort)v0.x), w0, a0); a1 = fmaf(bf2f((ushort)(v0.x >> 16)), w0, a1);
    a2 = fmaf(bf2f((ushort)v0.y), w0, a2); a3 = fmaf(bf2f((ushort)(v0.y >> 16)), w0, a3);
    b0 = fmaf(bf2f((ushort)v1.x), w1, b0); b1 = fmaf(bf2f((ushort)(v1.x >> 16)), w1, b1);
    b2 = fmaf(bf2f((ushort)v1.y), w1, b2); b3 = fmaf(bf2f((ushort)(v1.y >> 16)), w1, b3);
    c0 = fmaf(bf2f((ushort)v2.x), w2, c0); c1 = fmaf(bf2f((ushort)(v2.x >> 16)), w2, c1);
    c2 = fmaf(bf2f((ushort)v2.y), w2, c2); c3 = fmaf(bf2f((ushort)(v2.y >> 16)), w2, c3);
    d0 = fmaf(bf2f((ushort)v3.x), w3, d0); d1 = fmaf(bf2f((ushort)(v3.x >> 16)), w3, d1);
    d2 = fmaf(bf2f((ushort)v3.y), w3, d2); d3 = fmaf(bf2f((ushort)(v3.y >> 16)), w3, d3);
    a0 = fmaf(bf2f((ushort)v4.x), w4, a0); a1 = fmaf(bf2f((ushort)(v4.x >> 16)), w4, a1);
    a2 = fmaf(bf2f((ushort)v4.y), w4, a2); a3 = fmaf(bf2f((ushort)(v4.y >> 16)), w4, a3);
    b0 = fmaf(bf2f((ushort)v5.x), w5, b0); b1 = fmaf(bf2f((ushort)(v5.x >> 16)), w5, b1);
    b2 = fmaf(bf2f((ushort)v5.y), w5, b2); b3 = fmaf(bf2f((ushort)(v5.y >> 16)), w5, b3);
    c0 = fmaf(bf2f((ushort)v6.x), w6, c0); c1 = fmaf(bf2f((ushort)(v6.x >> 16)), w6, c1);
    c2 = fmaf(bf2f((ushort)v6.y), w6, c2); c3 = fmaf(bf2f((ushort)(v6.y >> 16)), w6, c3);
    d0 = fmaf(bf2f((ushort)v7.x), w7, d0); d1 = fmaf(bf2f((ushort)(v7.x >> 16)), w7, d1);
    d2 = fmaf(bf2f((ushort)v7.y), w7, d2); d3 = fmaf(bf2f((ushort)(v7.y >> 16)), w7, d3);
  }
  for (; e < eE; ++e) {
    unsigned p0 = ew[e];
    uint2 v0 = xs[(p0 >> 16) * 8 + cl];
    float w0 = h2f((ushort)p0);
    a0 = fmaf(bf2f((ushort)v0.x), w0, a0); a1 = fmaf(bf2f((ushort)(v0.x >> 16)), w0, a1);
    a2 = fmaf(bf2f((ushort)v0.y), w0, a2); a3 = fmaf(bf2f((ushort)(v0.y >> 16)), w0, a3);
  }
  a0 += b0 + c0 + d0; a1 += b1 + c1 + d1;
  a2 += b2 + c2 + d2; a3 += b3 + c3 + d3;
  os[node * 8 + cl] = make_uint2(packbf(a0, a1), packbf(a2, a3));
}

// ---------------- MFMA GEMM (128x128 tile, grid.y=2) ----------------
// A in cb layout [K/32][M][32] bf16; WT row-major [256][K] bf16.
// OUTCB: write h in cb layout [8][M][32]; else row-major [M][256].
template <int K, bool OUTCB>
__global__ __launch_bounds__(256) void gemm_mfma(
    const ushort* __restrict__ A, const ushort* __restrict__ WT,
    const float* __restrict__ bias, ushort* __restrict__ outb, int M) {
  __shared__ ushort smem[16384];  // 32 KB: A at 0, B at 8192
  const int tid = threadIdx.x;
  const int lane = tid & 63;
  const int wave = tid >> 6;
  const int wm = wave >> 1, wn = wave & 1;
  const int m0 = blockIdx.x * 128;
  const int n0 = blockIdx.y * 128;

  f4_t acc[4][4] = {};

  for (int k0 = 0; k0 < K; k0 += 64) {
    __syncthreads();
    // stage A tile [128][64]: LDS slot s -> logical row=s>>3, chunk=(s&7)^(row&7)
    #pragma unroll
    for (int is = 0; is < 4; ++is) {
      int s = is * 256 + tid;
      int row = s >> 3;
      int ch = (s & 7) ^ (row & 7);
      int k = k0 + ch * 8;
      long grow = m0 + row; if (grow > M - 1) grow = M - 1;
      const ushort* g = A + ((long)(k >> 5) * M + grow) * 32 + (k & 31);
      gload_lds16(g, &smem[(is * 256 + wave * 64) * 8]);
    }
    // stage B tile (WT rows n0..n0+127)
    #pragma unroll
    for (int is = 0; is < 4; ++is) {
      int s = is * 256 + tid;
      int row = s >> 3;
      int ch = (s & 7) ^ (row & 7);
      const ushort* g = WT + (long)(n0 + row) * K + k0 + ch * 8;
      gload_lds16(g, &smem[8192 + (is * 256 + wave * 64) * 8]);
    }
    asm volatile("s_waitcnt vmcnt(0)" ::: "memory");
    __syncthreads();
    #pragma unroll
    for (int ks = 0; ks < 2; ++ks) {
      s8_t af[4], bfr[4];
      #pragma unroll
      for (int mi = 0; mi < 4; ++mi) {
        int row = wm * 64 + mi * 16 + (lane & 15);
        int ch = (ks * 4 + (lane >> 4)) ^ (row & 7);
        af[mi] = *(const s8_t*)(&smem[row * 64 + ch * 8]);
      }
      #pragma unroll
      for (int ni = 0; ni < 4; ++ni) {
        int row = wn * 64 + ni * 16 + (lane & 15);
        int ch = (ks * 4 + (lane >> 4)) ^ (row & 7);
        bfr[ni] = *(const s8_t*)(&smem[8192 + row * 64 + ch * 8]);
      }
      #pragma unroll
      for (int mi = 0; mi < 4; ++mi)
        #pragma unroll
        for (int ni = 0; ni < 4; ++ni)
          acc[mi][ni] = mfma16(af[mi], bfr[ni], acc[mi][ni]);
    }
  }
  // epilogue: D col=lane&15, row=(lane>>4)*4+r
  #pragma unroll
  for (int ni = 0; ni < 4; ++ni) {
    int col = n0 + wn * 64 + ni * 16 + (lane & 15);
    float bb = bias[col];
    #pragma unroll
    for (int mi = 0; mi < 4; ++mi) {
      #pragma unroll
      for (int r = 0; r < 4; ++r) {
        int row = m0 + wm * 64 + mi * 16 + (lane >> 4) * 4 + r;
        if (row < M) {
          float v = fmaxf(acc[mi][ni][r] + bb, 0.0f);
          if (OUTCB)
            outb[((long)(col >> 5) * M + row) * 32 + (col & 31)] = f2bf(v);
          else
            outb[(long)row * HIDC + col] = f2bf(v);
        }
      }
    }
  }
}

// ---------------- pool via sorted-batch ranges ----------------
__global__ void find_bounds(const int* __restrict__ batch, int* __restrict__ gstart, int n) {
  int stride = gridDim.x * blockDim.x;
  for (int i = blockIdx.x * blockDim.x + threadIdx.x; i < n; i += stride) {
    int b = batch[i];
    if (i == 0) {
      for (int g = 0; g <= b; ++g) gstart[g] = 0;
    } else {
      int pb = batch[i - 1];
      if (pb != b)
        for (int g = pb + 1; g <= b; ++g) gstart[g] = i;
    }
    if (i == n - 1) {
      for (int g = b + 1; g <= NG; ++g) gstart[g] = n;
    }
  }
}

#define POOL_SPLIT 8
__global__ __launch_bounds__(HIDC) void pool_range_bf16(const ushort* __restrict__ h,
                                                        const int* __restrict__ gstart,
                                                        float* __restrict__ gsum) {
  int g = blockIdx.x;
  int s = blockIdx.y;
  int c = threadIdx.x;
  int s0 = gstart[g], s1 = gstart[g + 1];
  int len = s1 - s0;
  int chunk = (len + POOL_SPLIT - 1) / POOL_SPLIT;
  int i0 = s0 + s * chunk;
  int i1 = min(i0 + chunk, s1);
  float acc = 0.0f;
  for (int i = i0; i < i1; ++i) acc += bf2f(h[(long)i * HIDC + c]);
  if (i1 > i0) atomicAdd(&gsum[g * HIDC + c], acc);
}

// ---------------- final MLP + log_softmax ----------------
__global__ __launch_bounds__(64) void mlp_kernel(
    const float* __restrict__ gsum, const int* __restrict__ gstart,
    const float* __restrict__ Wl1, const float* __restrict__ bl1,
    const float* __restrict__ Wl2, const float* __restrict__ bl2,
    float* __restrict__ out) {
  __shared__ float g[HIDC];
  __shared__ float hid[64];
  __shared__ float logits[NCLS];
  __shared__ float red[2];
  int i = blockIdx.x;
  int t = threadIdx.x;
  int cnt = gstart[i + 1] - gstart[i];
  float inv = 1.0f / fmaxf((float)cnt, 1.0f);
  for (int c = t; c < HIDC; c += 64) g[c] = gsum[i * HIDC + c] * inv;
  __syncthreads();
  float acc = bl1[t];
  for (int c = 0; c < HIDC; ++c) acc = fmaf(g[c], Wl1[c * 64 + t], acc);
  hid[t] = fmaxf(acc, 0.0f);
  __syncthreads();
  if (t < NCLS) {
    float l = bl2[t];
    for (int c = 0; c < 64; ++c) l = fmaf(hid[c], Wl2[c * NCLS + t], l);
    logits[t] = l;
  }
  __syncthreads();
  if (t == 0) {
    float m = -1e30f;
    for (int k = 0; k < NCLS; ++k) m = fmaxf(m, logits[k]);
    float s = 0.f;
    for (int k = 0; k < NCLS; ++k) s += expf(logits[k] - m);
    red[0] = m;
    red[1] = logf(s);
  }
  __syncthreads();
  if (t < NCLS) out[i * NCLS + t] = logits[t] - red[0] - red[1];
}

extern "C" void kernel_launch(void* const* d_in, const int* in_sizes, int n_in,
                              void* d_out, int out_size, void* d_ws, size_t ws_size,
                              hipStream_t stream) {
  const float* x = (const float*)d_in[0];
  const int* edge_index = (const int*)d_in[1];
  const int* batch = (const int*)d_in[2];
  const float* W1 = (const float*)d_in[3];
  const float* b1 = (const float*)d_in[4];
  const float* W2 = (const float*)d_in[5];
  const float* b2 = (const float*)d_in[6];
  const float* Wl1 = (const float*)d_in[7];
  const float* bl1 = (const float*)d_in[8];
  const float* Wl2 = (const float*)d_in[9];
  const float* bl2 = (const float*)d_in[10];
  float* out = (float*)d_out;

  const int N = in_sizes[0] / INC;     // 50000
  const int E = in_sizes[1] / 2;       // 1600000
  const int* erow = edge_index;
  const int* ecol = edge_index + E;

  char* p = (char*)d_ws;
  auto alloc = [&](size_t bytes) {
    void* r = (void*)p;
    p += (bytes + 255) & ~(size_t)255;
    return r;
  };
  int* deg = (int*)alloc((size_t)N * 4);
  float* dis = (float*)alloc((size_t)N * 4);
  int* offsets = (int*)alloc((size_t)(N + 1) * 4);
  unsigned* ew = (unsigned*)alloc((size_t)E * 4);
  unsigned* part = (unsigned*)alloc((size_t)E * 4);
  int* hist = (int*)alloc((size_t)(NB * NBLK) * 4);
  int* histBase = (int*)alloc((size_t)(NB * NBLK + 1) * 4);
  float* gsum = (float*)alloc((size_t)NG * HIDC * 4);
  int* gstart = (int*)alloc((size_t)(NG + 1) * 4);
  int* blockTotals = (int*)alloc((size_t)256 * 4);
  ushort* W1T = (ushort*)alloc((size_t)INC * HIDC * 2);
  ushort* W2T = (ushort*)alloc((size_t)HIDC * HIDC * 2);
  unsigned* x_cb = (unsigned*)alloc((size_t)N * INC * 2);      // 12.8 MB [4][N][16u]
  unsigned* agg1_cb = (unsigned*)alloc((size_t)N * INC * 2);   // 12.8 MB [4][N][16u]
  unsigned* h1_cb = (unsigned*)alloc((size_t)N * HIDC * 2);    // 25.6 MB [8][N][16u]
  unsigned* agg2_cb = (unsigned*)alloc((size_t)N * HIDC * 2);  // 25.6 MB [8][N][16u]
  ushort* h2 = (ushort*)x_cb;  // reuse x_cb+agg1_cb (dead after GEMM1): 25.6 MB row-major

  hipMemsetAsync(gsum, 0, (size_t)NG * HIDC * 4, stream);

  // bucketed CSR build
  const int chunk = (E + NBLK - 1) / NBLK;
  edge_hist<<<NBLK, 256, 0, stream>>>(ecol, hist, E, chunk);
  {
    const int nh = NB * NBLK;
    const int nbh = (nh + SCAN_VPB - 1) / SCAN_VPB;
    scanA<<<nbh, SCAN_T, 0, stream>>>(hist, histBase, blockTotals, nh);
    scanB<<<1, 64, 0, stream>>>(blockTotals, nbh);
    scanC<<<(nh + 255) / 256, 256, 0, stream>>>(histBase, blockTotals, nh);
  }
  edge_partition<<<NBLK, 256, 0, stream>>>(erow, ecol, histBase, part, E, chunk);
  bucket_deg_dis<<<NB, 256, 0, stream>>>(part, histBase, deg, dis, N);
  {
    const int nb = (N + SCAN_VPB - 1) / SCAN_VPB;
    scanA<<<nb, SCAN_T, 0, stream>>>(deg, offsets, blockTotals, N);
    scanB<<<1, 64, 0, stream>>>(blockTotals, nb);
    scanC<<<(N + 255) / 256, 256, 0, stream>>>(offsets, blockTotals, N);
  }
  bucket_csr_ew<<<NB, 256, 0, stream>>>(part, histBase, offsets, dis, ew, N);

  // casts
  cast_x_cb<<<(N * 64 + 255) / 256, 256, 0, stream>>>(x, x_cb, N);
  {
    int tot = INC * HIDC + HIDC * HIDC;
    transpose_cast2<<<(tot + 255) / 256, 256, 0, stream>>>(W1, W1T, W2, W2T);
  }

  // layer 1: XCD-pinned cb aggregate (4 slices, one per XCD-pair), GEMM -> h1 cb
  {
    const int nb2 = (N + 63) / 64;  // covers 2 node-blocks per grid step
    aggregate_cb<1><<<nb2 << 3, 256, 0, stream>>>(
        (const uint2*)x_cb, dis, offsets, ew, (uint2*)agg1_cb, N);
  }
  {
    dim3 grid((N + 127) / 128, HIDC / 128);
    gemm_mfma<INC, true><<<grid, 256, 0, stream>>>(
        (const ushort*)agg1_cb, W1T, b1, (ushort*)h1_cb, N);
  }
  // layer 2: XCD-pinned cb aggregate (8 slices, one per XCD), GEMM -> h2 row-major
  {
    const int nodeblks = (N + 31) / 32;  // 1563
    aggregate_cb<0><<<nodeblks << 3, 256, 0, stream>>>(
        (const uint2*)h1_cb, dis, offsets, ew, (uint2*)agg2_cb, N);
  }
  {
    dim3 grid((N + 127) / 128, HIDC / 128);
    gemm_mfma<HIDC, false><<<grid, 256, 0, stream>>>(
        (const ushort*)agg2_cb, W2T, b2, h2, N);
  }
  // pool + MLP
  find_bounds<<<(N + 255) / 256, 256, 0, stream>>>(batch, gstart, N);
  {
    dim3 pgrid(NG, POOL_SPLIT);
    pool_range_bf16<<<pgrid, HIDC, 0, stream>>>(h2, gstart, gsum);
  }
  mlp_kernel<<<NG, 64, 0, stream>>>(gsum, gstart, Wl1, bl1, Wl2, bl2, out);
}

// Round 12
// 401.173 us; speedup vs baseline: 2.0274x; 1.0024x over previous
//
#include <hip/hip_runtime.h>
#include <hip/hip_bf16.h>
#include <math.h>

#define NN 50000
#define NG 128
#define INC 128
#define HIDC 256
#define NCLS 10

#define NBLK 256   // partition chunks
#define BSH 8      // bucket = col >> 8
#define NB 196     // ceil(50000/256) buckets

typedef _Float16 h8_t __attribute__((ext_vector_type(8)));  // 8 fp16 (4 VGPR)
typedef __attribute__((ext_vector_type(4))) float f4_t;     // 4 f32

__device__ inline f4_t mfma16(h8_t a, h8_t b, f4_t c) {
  return __builtin_amdgcn_mfma_f32_16x16x32_f16(a, b, c, 0, 0, 0);
}

__device__ inline ushort f2h(float f) {
  _Float16 h = (_Float16)f; return *(ushort*)&h;
}
__device__ inline float h2f(ushort u) {
  _Float16 h = *(_Float16*)&u; return (float)h;
}
__device__ inline float h_lo(unsigned u) {
  union { unsigned v; _Float16 h[2]; } c; c.v = u; return (float)c.h[0];
}
__device__ inline float h_hi(unsigned u) {
  union { unsigned v; _Float16 h[2]; } c; c.v = u; return (float)c.h[1];
}
__device__ inline unsigned packh(float a, float b) {
  return (unsigned)f2h(a) | ((unsigned)f2h(b) << 16);
}

__device__ inline void gload_lds16(const void* g, void* l) {
  __builtin_amdgcn_global_load_lds(
      (const __attribute__((address_space(1))) unsigned int*)g,
      (__attribute__((address_space(3))) unsigned int*)l, 16, 0, 0);
}

// ---------------- bucketed edge partition ----------------
__global__ __launch_bounds__(256) void edge_hist(const int* __restrict__ ecol,
                                                 int* __restrict__ hist, int E, int chunk) {
  __shared__ int h[NB];
  int blk = blockIdx.x;
  for (int i = threadIdx.x; i < NB; i += 256) h[i] = 0;
  __syncthreads();
  int e0 = blk * chunk, e1 = min(e0 + chunk, E);
  for (int e = e0 + threadIdx.x; e < e1; e += 256)
    atomicAdd(&h[ecol[e] >> BSH], 1);
  __syncthreads();
  for (int i = threadIdx.x; i < NB; i += 256) hist[i * NBLK + blk] = h[i];
}

// part entry: (row << 8) | (col & 255)
__global__ __launch_bounds__(256) void edge_partition(const int* __restrict__ erow,
                                                      const int* __restrict__ ecol,
                                                      const int* __restrict__ histBase,
                                                      unsigned* __restrict__ part,
                                                      int E, int chunk) {
  __shared__ int cur[NB];
  int blk = blockIdx.x;
  for (int i = threadIdx.x; i < NB; i += 256) cur[i] = histBase[i * NBLK + blk];
  __syncthreads();
  int e0 = blk * chunk, e1 = min(e0 + chunk, E);
  for (int e = e0 + threadIdx.x; e < e1; e += 256) {
    int c = ecol[e];
    int b = c >> BSH;
    int pos = atomicAdd(&cur[b], 1);
    part[pos] = ((unsigned)erow[e] << 8) | (unsigned)(c & 255);
  }
}

__global__ __launch_bounds__(256) void bucket_deg_dis(const unsigned* __restrict__ part,
                                                      const int* __restrict__ histBase,
                                                      int* __restrict__ deg,
                                                      float* __restrict__ dis, int N) {
  __shared__ int cnt[256];
  int b = blockIdx.x;
  cnt[threadIdx.x] = 0;
  __syncthreads();
  int s0 = histBase[b * NBLK];
  int s1 = histBase[(b + 1) * NBLK];
  for (int e = s0 + threadIdx.x; e < s1; e += 256)
    atomicAdd(&cnt[part[e] & 255], 1);
  __syncthreads();
  int node = (b << BSH) + threadIdx.x;
  if (node < N) {
    int d = cnt[threadIdx.x];
    deg[node] = d;
    dis[node] = rsqrtf((float)d + 1.0f);
  }
}

// writes packed edge: (src << 16) | fp16(dis[src]*dis[dst])
__global__ __launch_bounds__(256) void bucket_csr_ew(const unsigned* __restrict__ part,
                                                     const int* __restrict__ histBase,
                                                     const int* __restrict__ offsets,
                                                     const float* __restrict__ dis,
                                                     unsigned* __restrict__ ew, int N) {
  __shared__ int cur[256];
  __shared__ float sdis[256];
  int b = blockIdx.x;
  int node = (b << BSH) + threadIdx.x;
  cur[threadIdx.x] = (node < N) ? offsets[node] : 0;
  sdis[threadIdx.x] = (node < N) ? dis[node] : 0.0f;
  __syncthreads();
  int s0 = histBase[b * NBLK];
  int s1 = histBase[(b + 1) * NBLK];
  for (int e = s0 + threadIdx.x; e < s1; e += 256) {
    unsigned pv = part[e];
    int c = pv & 255;
    int r = (int)(pv >> 8);
    int pos = atomicAdd(&cur[c], 1);
    float w = dis[r] * sdis[c];
    ew[pos] = ((unsigned)r << 16) | (unsigned)f2h(w);
  }
}

// ---------------- multi-block exclusive scan ----------------
#define SCAN_T 256
#define SCAN_V 8
#define SCAN_VPB (SCAN_T * SCAN_V)  // 2048

__global__ __launch_bounds__(SCAN_T) void scanA(const int* __restrict__ deg,
                                                int* __restrict__ offsets,
                                                int* __restrict__ blockTotals, int n) {
  __shared__ int sm[SCAN_T];
  int b = blockIdx.x;
  int t = threadIdx.x;
  int base = b * SCAN_VPB + t * SCAN_V;
  int v[SCAN_V];
  int run = 0;
  #pragma unroll
  for (int j = 0; j < SCAN_V; ++j) {
    int idx = base + j;
    int d = (idx < n) ? deg[idx] : 0;
    run += d;
    v[j] = run;
  }
  sm[t] = run;
  __syncthreads();
  #pragma unroll
  for (int off = 1; off < SCAN_T; off <<= 1) {
    int x = (t >= off) ? sm[t - off] : 0;
    __syncthreads();
    sm[t] += x;
    __syncthreads();
  }
  int excl = (t == 0) ? 0 : sm[t - 1];
  #pragma unroll
  for (int j = 0; j < SCAN_V; ++j) {
    int idx = base + j;
    if (idx < n) offsets[idx + 1] = v[j] + excl;
  }
  if (t == SCAN_T - 1) blockTotals[b] = sm[t];
}

__global__ void scanB(int* __restrict__ blockTotals, int nb) {
  if (threadIdx.x == 0 && blockIdx.x == 0) {
    int run = 0;
    for (int i = 0; i < nb; ++i) {
      int v = blockTotals[i];
      blockTotals[i] = run;
      run += v;
    }
  }
}

__global__ void scanC(int* __restrict__ offsets, const int* __restrict__ blockTotals, int n) {
  int stride = gridDim.x * blockDim.x;
  for (int i = blockIdx.x * blockDim.x + threadIdx.x; i < n; i += stride) {
    offsets[i + 1] += blockTotals[i / SCAN_VPB];
    if (i == 0) offsets[0] = 0;
  }
}

// ---------------- casts ----------------
// x [N][128] f32 -> x_cb [4][N][16 uints] (cb-blocked fp16 pairs)
__global__ void cast_x_cb(const float* __restrict__ x, unsigned* __restrict__ xcb, int N) {
  int t = blockIdx.x * 256 + threadIdx.x;
  if (t >= N * 64) return;
  int n = t >> 6, pp = t & 63;  // pp = channel pair 0..63
  float v0 = x[(long)n * 128 + 2 * pp];
  float v1 = x[(long)n * 128 + 2 * pp + 1];
  xcb[((long)(pp >> 4) * N + n) * 16 + (pp & 15)] = packh(v0, v1);
}

// fused transpose+cast of W1 [128,256] and W2 [256,256] -> fp16
__global__ void transpose_cast2(const float* __restrict__ W1, ushort* __restrict__ W1T,
                                const float* __restrict__ W2, ushort* __restrict__ W2T) {
  int idx = blockIdx.x * blockDim.x + threadIdx.x;
  if (idx < INC * HIDC) {
    int k = idx / HIDC, n = idx % HIDC;
    W1T[(long)n * INC + k] = f2h(W1[idx]);
  }
  int i2 = idx - INC * HIDC;
  if (i2 >= 0 && i2 < HIDC * HIDC) {
    int k = i2 / HIDC, n = i2 % HIDC;
    W2T[(long)n * HIDC + k] = f2h(W2[i2]);
  }
}

// ---------------- channel-blocked aggregation, XCD-pinned slices, 8-deep ILP ----
// MODE 0 (layer 2, 8 slices): slice = blk&7, nodeblk = blk>>3.
// MODE 1 (layer 1, 4 slices): slice = (blk>>1)&3 (bits 2:1), sub = blk&1.
// Group = 8 lanes owns one node's 32-ch slice (8 x uint2 = 64B of fp16).
template <int MODE>
__global__ __launch_bounds__(256) void aggregate_cb(
    const uint2* __restrict__ xcb, const float* __restrict__ dis,
    const int* __restrict__ offsets, const unsigned* __restrict__ ew,
    uint2* __restrict__ outcb, int N) {
  int blk = blockIdx.x;
  int slice, nb;
  if (MODE == 0) { slice = blk & 7; nb = blk >> 3; }
  else           { slice = (blk >> 1) & 3; nb = ((blk >> 3) << 1) | (blk & 1); }
  int node = nb * 32 + (threadIdx.x >> 3);
  if (node >= N) return;
  int cl = threadIdx.x & 7;  // uint2 index within row slice
  const uint2* xs = xcb + (long)slice * N * 8;
  uint2* os = outcb + (long)slice * N * 8;
  float di = dis[node];
  float dd = di * di;
  uint2 sv = xs[node * 8 + cl];
  float a0 = h_lo(sv.x) * dd;
  float a1 = h_hi(sv.x) * dd;
  float a2 = h_lo(sv.y) * dd;
  float a3 = h_hi(sv.y) * dd;
  float b0 = 0, b1 = 0, b2 = 0, b3 = 0;
  float c0 = 0, c1 = 0, c2 = 0, c3 = 0;
  float d0 = 0, d1 = 0, d2 = 0, d3 = 0;
  int e = offsets[node], eE = offsets[node + 1];
  for (; e + 7 < eE; e += 8) {
    unsigned p0 = ew[e],     p1 = ew[e + 1], p2 = ew[e + 2], p3 = ew[e + 3];
    unsigned p4 = ew[e + 4], p5 = ew[e + 5], p6 = ew[e + 6], p7 = ew[e + 7];
    uint2 v0 = xs[(p0 >> 16) * 8 + cl];
    uint2 v1 = xs[(p1 >> 16) * 8 + cl];
    uint2 v2 = xs[(p2 >> 16) * 8 + cl];
    uint2 v3 = xs[(p3 >> 16) * 8 + cl];
    uint2 v4 = xs[(p4 >> 16) * 8 + cl];
    uint2 v5 = xs[(p5 >> 16) * 8 + cl];
    uint2 v6 = xs[(p6 >> 16) * 8 + cl];
    uint2 v7 = xs[(p7 >> 16) * 8 + cl];
    float w0 = h2f((ushort)p0), w1 = h2f((ushort)p1);
    float w2 = h2f((ushort)p2), w3 = h2f((ushort)p3);
    float w4 = h2f((ushort)p4), w5 = h2f((ushort)p5);
    float w6 = h2f((ushort)p6), w7 = h2f((ushort)p7);
    a0 = fmaf(h_lo(v0.x), w0, a0); a1 = fmaf(h_hi(v0.x), w0, a1);
    a2 = fmaf(h_lo(v0.y), w0, a2); a3 = fmaf(h_hi(v0.y), w0, a3);
    b0 = fmaf(h_lo(v1.x), w1, b0); b1 = fmaf(h_hi(v1.x), w1, b1);
    b2 = fmaf(h_lo(v1.y), w1, b2); b3 = fmaf(h_hi(v1.y), w1, b3);
    c0 = fmaf(h_lo(v2.x), w2, c0); c1 = fmaf(h_hi(v2.x), w2, c1);
    c2 = fmaf(h_lo(v2.y), w2, c2); c3 = fmaf(h_hi(v2.y), w2, c3);
    d0 = fmaf(h_lo(v3.x), w3, d0); d1 = fmaf(h_hi(v3.x), w3, d1);
    d2 = fmaf(h_lo(v3.y), w3, d2); d3 = fmaf(h_hi(v3.y), w3, d3);
    a0 = fmaf(h_lo(v4.x), w4, a0); a1 = fmaf(h_hi(v4.x), w4, a1);
    a2 = fmaf(h_lo(v4.y), w4, a2); a3 = fmaf(h_hi(v4.y), w4, a3);
    b0 = fmaf(h_lo(v5.x), w5, b0); b1 = fmaf(h_hi(v5.x), w5, b1);
    b2 = fmaf(h_lo(v5.y), w5, b2); b3 = fmaf(h_hi(v5.y), w5, b3);
    c0 = fmaf(h_lo(v6.x), w6, c0); c1 = fmaf(h_hi(v6.x), w6, c1);
    c2 = fmaf(h_lo(v6.y), w6, c2); c3 = fmaf(h_hi(v6.y), w6, c3);
    d0 = fmaf(h_lo(v7.x), w7, d0); d1 = fmaf(h_hi(v7.x), w7, d1);
    d2 = fmaf(h_lo(v7.y), w7, d2); d3 = fmaf(h_hi(v7.y), w7, d3);
  }
  for (; e < eE; ++e) {
    unsigned p0 = ew[e];
    uint2 v0 = xs[(p0 >> 16) * 8 + cl];
    float w0 = h2f((ushort)p0);
    a0 = fmaf(h_lo(v0.x), w0, a0); a1 = fmaf(h_hi(v0.x), w0, a1);
    a2 = fmaf(h_lo(v0.y), w0, a2); a3 = fmaf(h_hi(v0.y), w0, a3);
  }
  a0 += b0 + c0 + d0; a1 += b1 + c1 + d1;
  a2 += b2 + c2 + d2; a3 += b3 + c3 + d3;
  os[node * 8 + cl] = make_uint2(packh(a0, a1), packh(a2, a3));
}

// ---------------- MFMA GEMM (128x128 tile, grid.y=2), fp16 ----------------
// A in cb layout [K/32][M][32] fp16; WT row-major [256][K] fp16.
// OUTCB: write h in cb layout [8][M][32]; else row-major [M][256].
template <int K, bool OUTCB>
__global__ __launch_bounds__(256) void gemm_mfma(
    const ushort* __restrict__ A, const ushort* __restrict__ WT,
    const float* __restrict__ bias, ushort* __restrict__ outb, int M) {
  __shared__ ushort smem[16384];  // 32 KB: A at 0, B at 8192
  const int tid = threadIdx.x;
  const int lane = tid & 63;
  const int wave = tid >> 6;
  const int wm = wave >> 1, wn = wave & 1;
  const int m0 = blockIdx.x * 128;
  const int n0 = blockIdx.y * 128;

  f4_t acc[4][4] = {};

  for (int k0 = 0; k0 < K; k0 += 64) {
    __syncthreads();
    // stage A tile [128][64]: LDS slot s -> logical row=s>>3, chunk=(s&7)^(row&7)
    #pragma unroll
    for (int is = 0; is < 4; ++is) {
      int s = is * 256 + tid;
      int row = s >> 3;
      int ch = (s & 7) ^ (row & 7);
      int k = k0 + ch * 8;
      long grow = m0 + row; if (grow > M - 1) grow = M - 1;
      const ushort* g = A + ((long)(k >> 5) * M + grow) * 32 + (k & 31);
      gload_lds16(g, &smem[(is * 256 + wave * 64) * 8]);
    }
    // stage B tile (WT rows n0..n0+127)
    #pragma unroll
    for (int is = 0; is < 4; ++is) {
      int s = is * 256 + tid;
      int row = s >> 3;
      int ch = (s & 7) ^ (row & 7);
      const ushort* g = WT + (long)(n0 + row) * K + k0 + ch * 8;
      gload_lds16(g, &smem[8192 + (is * 256 + wave * 64) * 8]);
    }
    asm volatile("s_waitcnt vmcnt(0)" ::: "memory");
    __syncthreads();
    #pragma unroll
    for (int ks = 0; ks < 2; ++ks) {
      h8_t af[4], bfr[4];
      #pragma unroll
      for (int mi = 0; mi < 4; ++mi) {
        int row = wm * 64 + mi * 16 + (lane & 15);
        int ch = (ks * 4 + (lane >> 4)) ^ (row & 7);
        af[mi] = *(const h8_t*)(&smem[row * 64 + ch * 8]);
      }
      #pragma unroll
      for (int ni = 0; ni < 4; ++ni) {
        int row = wn * 64 + ni * 16 + (lane & 15);
        int ch = (ks * 4 + (lane >> 4)) ^ (row & 7);
        bfr[ni] = *(const h8_t*)(&smem[8192 + row * 64 + ch * 8]);
      }
      #pragma unroll
      for (int mi = 0; mi < 4; ++mi)
        #pragma unroll
        for (int ni = 0; ni < 4; ++ni)
          acc[mi][ni] = mfma16(af[mi], bfr[ni], acc[mi][ni]);
    }
  }
  // epilogue: D col=lane&15, row=(lane>>4)*4+r
  #pragma unroll
  for (int ni = 0; ni < 4; ++ni) {
    int col = n0 + wn * 64 + ni * 16 + (lane & 15);
    float bb = bias[col];
    #pragma unroll
    for (int mi = 0; mi < 4; ++mi) {
      #pragma unroll
      for (int r = 0; r < 4; ++r) {
        int row = m0 + wm * 64 + mi * 16 + (lane >> 4) * 4 + r;
        if (row < M) {
          float v = fmaxf(acc[mi][ni][r] + bb, 0.0f);
          if (OUTCB)
            outb[((long)(col >> 5) * M + row) * 32 + (col & 31)] = f2h(v);
          else
            outb[(long)row * HIDC + col] = f2h(v);
        }
      }
    }
  }
}

// ---------------- pool via sorted-batch ranges ----------------
__global__ void find_bounds(const int* __restrict__ batch, int* __restrict__ gstart, int n) {
  int stride = gridDim.x * blockDim.x;
  for (int i = blockIdx.x * blockDim.x + threadIdx.x; i < n; i += stride) {
    int b = batch[i];
    if (i == 0) {
      for (int g = 0; g <= b; ++g) gstart[g] = 0;
    } else {
      int pb = batch[i - 1];
      if (pb != b)
        for (int g = pb + 1; g <= b; ++g) gstart[g] = i;
    }
    if (i == n - 1) {
      for (int g = b + 1; g <= NG; ++g) gstart[g] = n;
    }
  }
}

#define POOL_SPLIT 8
__global__ __launch_bounds__(HIDC) void pool_range_f16(const ushort* __restrict__ h,
                                                       const int* __restrict__ gstart,
                                                       float* __restrict__ gsum) {
  int g = blockIdx.x;
  int s = blockIdx.y;
  int c = threadIdx.x;
  int s0 = gstart[g], s1 = gstart[g + 1];
  int len = s1 - s0;
  int chunk = (len + POOL_SPLIT - 1) / POOL_SPLIT;
  int i0 = s0 + s * chunk;
  int i1 = min(i0 + chunk, s1);
  float acc = 0.0f;
  for (int i = i0; i < i1; ++i) acc += h2f(h[(long)i * HIDC + c]);
  if (i1 > i0) atomicAdd(&gsum[g * HIDC + c], acc);
}

// ---------------- final MLP + log_softmax ----------------
__global__ __launch_bounds__(64) void mlp_kernel(
    const float* __restrict__ gsum, const int* __restrict__ gstart,
    const float* __restrict__ Wl1, const float* __restrict__ bl1,
    const float* __restrict__ Wl2, const float* __restrict__ bl2,
    float* __restrict__ out) {
  __shared__ float g[HIDC];
  __shared__ float hid[64];
  __shared__ float logits[NCLS];
  __shared__ float red[2];
  int i = blockIdx.x;
  int t = threadIdx.x;
  int cnt = gstart[i + 1] - gstart[i];
  float inv = 1.0f / fmaxf((float)cnt, 1.0f);
  for (int c = t; c < HIDC; c += 64) g[c] = gsum[i * HIDC + c] * inv;
  __syncthreads();
  float acc = bl1[t];
  for (int c = 0; c < HIDC; ++c) acc = fmaf(g[c], Wl1[c * 64 + t], acc);
  hid[t] = fmaxf(acc, 0.0f);
  __syncthreads();
  if (t < NCLS) {
    float l = bl2[t];
    for (int c = 0; c < 64; ++c) l = fmaf(hid[c], Wl2[c * NCLS + t], l);
    logits[t] = l;
  }
  __syncthreads();
  if (t == 0) {
    float m = -1e30f;
    for (int k = 0; k < NCLS; ++k) m = fmaxf(m, logits[k]);
    float s = 0.f;
    for (int k = 0; k < NCLS; ++k) s += expf(logits[k] - m);
    red[0] = m;
    red[1] = logf(s);
  }
  __syncthreads();
  if (t < NCLS) out[i * NCLS + t] = logits[t] - red[0] - red[1];
}

extern "C" void kernel_launch(void* const* d_in, const int* in_sizes, int n_in,
                              void* d_out, int out_size, void* d_ws, size_t ws_size,
                              hipStream_t stream) {
  const float* x = (const float*)d_in[0];
  const int* edge_index = (const int*)d_in[1];
  const int* batch = (const int*)d_in[2];
  const float* W1 = (const float*)d_in[3];
  const float* b1 = (const float*)d_in[4];
  const float* W2 = (const float*)d_in[5];
  const float* b2 = (const float*)d_in[6];
  const float* Wl1 = (const float*)d_in[7];
  const float* bl1 = (const float*)d_in[8];
  const float* Wl2 = (const float*)d_in[9];
  const float* bl2 = (const float*)d_in[10];
  float* out = (float*)d_out;

  const int N = in_sizes[0] / INC;     // 50000
  const int E = in_sizes[1] / 2;       // 1600000
  const int* erow = edge_index;
  const int* ecol = edge_index + E;

  char* p = (char*)d_ws;
  auto alloc = [&](size_t bytes) {
    void* r = (void*)p;
    p += (bytes + 255) & ~(size_t)255;
    return r;
  };
  int* deg = (int*)alloc((size_t)N * 4);
  float* dis = (float*)alloc((size_t)N * 4);
  int* offsets = (int*)alloc((size_t)(N + 1) * 4);
  unsigned* ew = (unsigned*)alloc((size_t)E * 4);
  unsigned* part = (unsigned*)alloc((size_t)E * 4);
  int* hist = (int*)alloc((size_t)(NB * NBLK) * 4);
  int* histBase = (int*)alloc((size_t)(NB * NBLK + 1) * 4);
  float* gsum = (float*)alloc((size_t)NG * HIDC * 4);
  int* gstart = (int*)alloc((size_t)(NG + 1) * 4);
  int* blockTotals = (int*)alloc((size_t)256 * 4);
  ushort* W1T = (ushort*)alloc((size_t)INC * HIDC * 2);
  ushort* W2T = (ushort*)alloc((size_t)HIDC * HIDC * 2);
  unsigned* x_cb = (unsigned*)alloc((size_t)N * INC * 2);      // 12.8 MB [4][N][16u]
  unsigned* agg1_cb = (unsigned*)alloc((size_t)N * INC * 2);   // 12.8 MB [4][N][16u]
  unsigned* h1_cb = (unsigned*)alloc((size_t)N * HIDC * 2);    // 25.6 MB [8][N][16u]
  unsigned* agg2_cb = (unsigned*)alloc((size_t)N * HIDC * 2);  // 25.6 MB [8][N][16u]
  ushort* h2 = (ushort*)x_cb;  // reuse x_cb+agg1_cb (dead after GEMM1): 25.6 MB row-major

  hipMemsetAsync(gsum, 0, (size_t)NG * HIDC * 4, stream);

  // bucketed CSR build
  const int chunk = (E + NBLK - 1) / NBLK;
  edge_hist<<<NBLK, 256, 0, stream>>>(ecol, hist, E, chunk);
  {
    const int nh = NB * NBLK;
    const int nbh = (nh + SCAN_VPB - 1) / SCAN_VPB;
    scanA<<<nbh, SCAN_T, 0, stream>>>(hist, histBase, blockTotals, nh);
    scanB<<<1, 64, 0, stream>>>(blockTotals, nbh);
    scanC<<<(nh + 255) / 256, 256, 0, stream>>>(histBase, blockTotals, nh);
  }
  edge_partition<<<NBLK, 256, 0, stream>>>(erow, ecol, histBase, part, E, chunk);
  bucket_deg_dis<<<NB, 256, 0, stream>>>(part, histBase, deg, dis, N);
  {
    const int nb = (N + SCAN_VPB - 1) / SCAN_VPB;
    scanA<<<nb, SCAN_T, 0, stream>>>(deg, offsets, blockTotals, N);
    scanB<<<1, 64, 0, stream>>>(blockTotals, nb);
    scanC<<<(N + 255) / 256, 256, 0, stream>>>(offsets, blockTotals, N);
  }
  bucket_csr_ew<<<NB, 256, 0, stream>>>(part, histBase, offsets, dis, ew, N);

  // casts
  cast_x_cb<<<(N * 64 + 255) / 256, 256, 0, stream>>>(x, x_cb, N);
  {
    int tot = INC * HIDC + HIDC * HIDC;
    transpose_cast2<<<(tot + 255) / 256, 256, 0, stream>>>(W1, W1T, W2, W2T);
  }

  // layer 1: XCD-pinned cb aggregate (4 slices, one per XCD-pair), GEMM -> h1 cb
  {
    const int nb2 = (N + 63) / 64;
    aggregate_cb<1><<<nb2 << 3, 256, 0, stream>>>(
        (const uint2*)x_cb, dis, offsets, ew, (uint2*)agg1_cb, N);
  }
  {
    dim3 grid((N + 127) / 128, HIDC / 128);
    gemm_mfma<INC, true><<<grid, 256, 0, stream>>>(
        (const ushort*)agg1_cb, W1T, b1, (ushort*)h1_cb, N);
  }
  // layer 2: XCD-pinned cb aggregate (8 slices, one per XCD), GEMM -> h2 row-major
  {
    const int nodeblks = (N + 31) / 32;
    aggregate_cb<0><<<nodeblks << 3, 256, 0, stream>>>(
        (const uint2*)h1_cb, dis, offsets, ew, (uint2*)agg2_cb, N);
  }
  {
    dim3 grid((N + 127) / 128, HIDC / 128);
    gemm_mfma<HIDC, false><<<grid, 256, 0, stream>>>(
        (const ushort*)agg2_cb, W2T, b2, h2, N);
  }
  // pool + MLP
  find_bounds<<<(N + 255) / 256, 256, 0, stream>>>(batch, gstart, N);
  {
    dim3 pgrid(NG, POOL_SPLIT);
    pool_range_f16<<<pgrid, HIDC, 0, stream>>>(h2, gstart, gsum);
  }
  mlp_kernel<<<NG, 64, 0, stream>>>(gsum, gstart, Wl1, bl1, Wl2, bl2, out);
}

// Round 13
// 396.804 us; speedup vs baseline: 2.0497x; 1.0110x over previous
//
#include <hip/hip_runtime.h>
#include <hip/hip_bf16.h>
#include <math.h>

#define NN 50000
#define NG 128
#define INC 128
#define HIDC 256
#define NCLS 10

#define NBLK 256   // partition chunks
#define BSH 8      // bucket = col >> 8
#define NB 196     // ceil(50000/256) buckets

typedef _Float16 h8_t __attribute__((ext_vector_type(8)));  // 8 fp16 (4 VGPR)
typedef _Float16 h2_t __attribute__((ext_vector_type(2)));  // packed half2
typedef __attribute__((ext_vector_type(4))) float f4_t;     // 4 f32

__device__ inline f4_t mfma16(h8_t a, h8_t b, f4_t c) {
  return __builtin_amdgcn_mfma_f32_16x16x32_f16(a, b, c, 0, 0, 0);
}

__device__ inline ushort f2h(float f) {
  _Float16 h = (_Float16)f; return *(ushort*)&h;
}
__device__ inline float h2f(ushort u) {
  _Float16 h = *(_Float16*)&u; return (float)h;
}

union U2 { uint2 u; struct { h2_t x, y; } h; };
union UW { unsigned u; h2_t h; };

__device__ inline void gload_lds16(const void* g, void* l) {
  __builtin_amdgcn_global_load_lds(
      (const __attribute__((address_space(1))) unsigned int*)g,
      (__attribute__((address_space(3))) unsigned int*)l, 16, 0, 0);
}

__device__ inline int lbound(const int* __restrict__ a, int n, int key) {
  int lo = 0, hi = n;
  while (lo < hi) { int m = (lo + hi) >> 1; if (a[m] < key) lo = m + 1; else hi = m; }
  return lo;
}

// ---------------- bucketed edge partition ----------------
__global__ __launch_bounds__(256) void edge_hist(const int* __restrict__ ecol,
                                                 int* __restrict__ hist, int E, int chunk) {
  __shared__ int h[NB];
  int blk = blockIdx.x;
  for (int i = threadIdx.x; i < NB; i += 256) h[i] = 0;
  __syncthreads();
  int e0 = blk * chunk, e1 = min(e0 + chunk, E);
  for (int e = e0 + threadIdx.x; e < e1; e += 256)
    atomicAdd(&h[ecol[e] >> BSH], 1);
  __syncthreads();
  for (int i = threadIdx.x; i < NB; i += 256) hist[i * NBLK + blk] = h[i];
}

// part entry: (row << 8) | (col & 255)
__global__ __launch_bounds__(256) void edge_partition(const int* __restrict__ erow,
                                                      const int* __restrict__ ecol,
                                                      const int* __restrict__ histBase,
                                                      unsigned* __restrict__ part,
                                                      int E, int chunk) {
  __shared__ int cur[NB];
  int blk = blockIdx.x;
  for (int i = threadIdx.x; i < NB; i += 256) cur[i] = histBase[i * NBLK + blk];
  __syncthreads();
  int e0 = blk * chunk, e1 = min(e0 + chunk, E);
  for (int e = e0 + threadIdx.x; e < e1; e += 256) {
    int c = ecol[e];
    int b = c >> BSH;
    int pos = atomicAdd(&cur[b], 1);
    part[pos] = ((unsigned)erow[e] << 8) | (unsigned)(c & 255);
  }
}

// fused: per-bucket degree count -> LDS exclusive scan -> offsets + dis
// offsets[node] = histBase[b*NBLK] + prefix(cnt[0..c-1]); offsets[N]=E falls out.
__global__ __launch_bounds__(256) void bucket_off_dis(const unsigned* __restrict__ part,
                                                      const int* __restrict__ histBase,
                                                      int* __restrict__ offsets,
                                                      float* __restrict__ dis, int N) {
  __shared__ int cnt[256];
  __shared__ int sm[256];
  int b = blockIdx.x, t = threadIdx.x;
  cnt[t] = 0;
  __syncthreads();
  int s0 = histBase[b * NBLK];
  int s1 = histBase[(b + 1) * NBLK];
  for (int e = s0 + t; e < s1; e += 256)
    atomicAdd(&cnt[part[e] & 255], 1);
  __syncthreads();
  int v = cnt[t];
  sm[t] = v;
  __syncthreads();
  #pragma unroll
  for (int off = 1; off < 256; off <<= 1) {
    int x = (t >= off) ? sm[t - off] : 0;
    __syncthreads();
    sm[t] += x;
    __syncthreads();
  }
  int excl = (t == 0) ? 0 : sm[t - 1];
  int node = (b << BSH) + t;
  if (node < N) {
    offsets[node] = s0 + excl;
    dis[node] = rsqrtf((float)v + 1.0f);
  } else if (node == N) {
    offsets[N] = s0 + excl;  // == E
  }
}

// writes packed edge: (src << 16) | fp16(dis[src]*dis[dst])
__global__ __launch_bounds__(256) void bucket_csr_ew(const unsigned* __restrict__ part,
                                                     const int* __restrict__ histBase,
                                                     const int* __restrict__ offsets,
                                                     const float* __restrict__ dis,
                                                     unsigned* __restrict__ ew, int N) {
  __shared__ int cur[256];
  __shared__ float sdis[256];
  int b = blockIdx.x;
  int node = (b << BSH) + threadIdx.x;
  cur[threadIdx.x] = (node < N) ? offsets[node] : 0;
  sdis[threadIdx.x] = (node < N) ? dis[node] : 0.0f;
  __syncthreads();
  int s0 = histBase[b * NBLK];
  int s1 = histBase[(b + 1) * NBLK];
  for (int e = s0 + threadIdx.x; e < s1; e += 256) {
    unsigned pv = part[e];
    int c = pv & 255;
    int r = (int)(pv >> 8);
    int pos = atomicAdd(&cur[c], 1);
    float w = dis[r] * sdis[c];
    ew[pos] = ((unsigned)r << 16) | (unsigned)f2h(w);
  }
}

// ---------------- multi-block exclusive scan (for histBase only) ----------------
#define SCAN_T 256
#define SCAN_V 8
#define SCAN_VPB (SCAN_T * SCAN_V)  // 2048

__global__ __launch_bounds__(SCAN_T) void scanA(const int* __restrict__ deg,
                                                int* __restrict__ offsets,
                                                int* __restrict__ blockTotals, int n) {
  __shared__ int sm[SCAN_T];
  int b = blockIdx.x;
  int t = threadIdx.x;
  int base = b * SCAN_VPB + t * SCAN_V;
  int v[SCAN_V];
  int run = 0;
  #pragma unroll
  for (int j = 0; j < SCAN_V; ++j) {
    int idx = base + j;
    int d = (idx < n) ? deg[idx] : 0;
    run += d;
    v[j] = run;
  }
  sm[t] = run;
  __syncthreads();
  #pragma unroll
  for (int off = 1; off < SCAN_T; off <<= 1) {
    int x = (t >= off) ? sm[t - off] : 0;
    __syncthreads();
    sm[t] += x;
    __syncthreads();
  }
  int excl = (t == 0) ? 0 : sm[t - 1];
  #pragma unroll
  for (int j = 0; j < SCAN_V; ++j) {
    int idx = base + j;
    if (idx < n) offsets[idx + 1] = v[j] + excl;
  }
  if (t == SCAN_T - 1) blockTotals[b] = sm[t];
}

__global__ void scanB(int* __restrict__ blockTotals, int nb) {
  if (threadIdx.x == 0 && blockIdx.x == 0) {
    int run = 0;
    for (int i = 0; i < nb; ++i) {
      int v = blockTotals[i];
      blockTotals[i] = run;
      run += v;
    }
  }
}

__global__ void scanC(int* __restrict__ offsets, const int* __restrict__ blockTotals, int n) {
  int stride = gridDim.x * blockDim.x;
  for (int i = blockIdx.x * blockDim.x + threadIdx.x; i < n; i += stride) {
    offsets[i + 1] += blockTotals[i / SCAN_VPB];
    if (i == 0) offsets[0] = 0;
  }
}

// ---------------- fused casts ----------------
// region 1: x [N][128] f32 -> x_cb [4][N][16u] (fp16 pairs)
// region 2: W1 transpose-cast; region 3: W2 transpose-cast
__global__ void cast_all(const float* __restrict__ x, unsigned* __restrict__ xcb,
                         const float* __restrict__ W1, ushort* __restrict__ W1T,
                         const float* __restrict__ W2, ushort* __restrict__ W2T, int N) {
  int idx = blockIdx.x * 256 + threadIdx.x;
  int nx = N * 64;
  if (idx < nx) {
    int n = idx >> 6, pp = idx & 63;
    float v0 = x[(long)n * 128 + 2 * pp];
    float v1 = x[(long)n * 128 + 2 * pp + 1];
    xcb[((long)(pp >> 4) * N + n) * 16 + (pp & 15)] =
        (unsigned)f2h(v0) | ((unsigned)f2h(v1) << 16);
    return;
  }
  int i1 = idx - nx;
  if (i1 < INC * HIDC) {
    int k = i1 / HIDC, n = i1 % HIDC;
    W1T[(long)n * INC + k] = f2h(W1[i1]);
    return;
  }
  int i2 = i1 - INC * HIDC;
  if (i2 < HIDC * HIDC) {
    int k = i2 / HIDC, n = i2 % HIDC;
    W2T[(long)n * HIDC + k] = f2h(W2[i2]);
  }
}

// ---------------- channel-blocked aggregation, XCD-pinned, packed-fp16 math ----
// MODE 0 (layer 2, 8 slices): slice = blk&7, nodeblk = blk>>3.
// MODE 1 (layer 1, 4 slices): slice = (blk>>1)&3, sub = blk&1.
// Group = 8 lanes owns one node's 32-ch slice (8 x uint2 = 64B of fp16).
// fp16 packed accumulators (v_pk_fma_f16): 2 ch per instruction.
template <int MODE>
__global__ __launch_bounds__(256) void aggregate_cb(
    const uint2* __restrict__ xcb, const float* __restrict__ dis,
    const int* __restrict__ offsets, const unsigned* __restrict__ ew,
    uint2* __restrict__ outcb, int N) {
  int blk = blockIdx.x;
  int slice, nb;
  if (MODE == 0) { slice = blk & 7; nb = blk >> 3; }
  else           { slice = (blk >> 1) & 3; nb = ((blk >> 3) << 1) | (blk & 1); }
  int node = nb * 32 + (threadIdx.x >> 3);
  if (node >= N) return;
  int cl = threadIdx.x & 7;
  const uint2* xs = xcb + (long)slice * N * 8;
  uint2* os = outcb + (long)slice * N * 8;
  float di = dis[node];
  _Float16 ddh = (_Float16)(di * di);
  h2_t dd2 = {ddh, ddh};
  U2 sv; sv.u = xs[node * 8 + cl];
  h2_t ax = sv.h.x * dd2, ay = sv.h.y * dd2;
  h2_t bx = {0, 0}, by = {0, 0};
  h2_t cx = {0, 0}, cy = {0, 0};
  h2_t dx = {0, 0}, dy = {0, 0};
  int e = offsets[node], eE = offsets[node + 1];
  for (; e + 7 < eE; e += 8) {
    unsigned p0 = ew[e],     p1 = ew[e + 1], p2 = ew[e + 2], p3 = ew[e + 3];
    unsigned p4 = ew[e + 4], p5 = ew[e + 5], p6 = ew[e + 6], p7 = ew[e + 7];
    U2 v0, v1, v2, v3, v4, v5, v6, v7;
    v0.u = xs[(p0 >> 16) * 8 + cl];
    v1.u = xs[(p1 >> 16) * 8 + cl];
    v2.u = xs[(p2 >> 16) * 8 + cl];
    v3.u = xs[(p3 >> 16) * 8 + cl];
    v4.u = xs[(p4 >> 16) * 8 + cl];
    v5.u = xs[(p5 >> 16) * 8 + cl];
    v6.u = xs[(p6 >> 16) * 8 + cl];
    v7.u = xs[(p7 >> 16) * 8 + cl];
    UW q0, q1, q2, q3, q4, q5, q6, q7;
    q0.u = p0; q1.u = p1; q2.u = p2; q3.u = p3;
    q4.u = p4; q5.u = p5; q6.u = p6; q7.u = p7;
    h2_t w0 = {q0.h[0], q0.h[0]}, w1 = {q1.h[0], q1.h[0]};
    h2_t w2 = {q2.h[0], q2.h[0]}, w3 = {q3.h[0], q3.h[0]};
    h2_t w4 = {q4.h[0], q4.h[0]}, w5 = {q5.h[0], q5.h[0]};
    h2_t w6 = {q6.h[0], q6.h[0]}, w7 = {q7.h[0], q7.h[0]};
    ax = v0.h.x * w0 + ax; ay = v0.h.y * w0 + ay;
    bx = v1.h.x * w1 + bx; by = v1.h.y * w1 + by;
    cx = v2.h.x * w2 + cx; cy = v2.h.y * w2 + cy;
    dx = v3.h.x * w3 + dx; dy = v3.h.y * w3 + dy;
    ax = v4.h.x * w4 + ax; ay = v4.h.y * w4 + ay;
    bx = v5.h.x * w5 + bx; by = v5.h.y * w5 + by;
    cx = v6.h.x * w6 + cx; cy = v6.h.y * w6 + cy;
    dx = v7.h.x * w7 + dx; dy = v7.h.y * w7 + dy;
  }
  for (; e < eE; ++e) {
    unsigned p0 = ew[e];
    U2 v0; v0.u = xs[(p0 >> 16) * 8 + cl];
    UW q0; q0.u = p0;
    h2_t w0 = {q0.h[0], q0.h[0]};
    ax = v0.h.x * w0 + ax; ay = v0.h.y * w0 + ay;
  }
  ax = ax + bx + cx + dx;
  ay = ay + by + cy + dy;
  U2 o; o.h.x = ax; o.h.y = ay;
  os[node * 8 + cl] = o.u;
}

// ---------------- MFMA GEMM (128x128 tile, grid.y=2), fp16 ----------------
// A in cb layout [K/32][M][32] fp16; WT row-major [256][K] fp16.
// OUTCB: write h in cb layout [8][M][32]; else row-major [M][256].
template <int K, bool OUTCB>
__global__ __launch_bounds__(256) void gemm_mfma(
    const ushort* __restrict__ A, const ushort* __restrict__ WT,
    const float* __restrict__ bias, ushort* __restrict__ outb, int M) {
  __shared__ ushort smem[16384];  // 32 KB: A at 0, B at 8192
  const int tid = threadIdx.x;
  const int lane = tid & 63;
  const int wave = tid >> 6;
  const int wm = wave >> 1, wn = wave & 1;
  const int m0 = blockIdx.x * 128;
  const int n0 = blockIdx.y * 128;

  f4_t acc[4][4] = {};

  for (int k0 = 0; k0 < K; k0 += 64) {
    __syncthreads();
    #pragma unroll
    for (int is = 0; is < 4; ++is) {
      int s = is * 256 + tid;
      int row = s >> 3;
      int ch = (s & 7) ^ (row & 7);
      int k = k0 + ch * 8;
      long grow = m0 + row; if (grow > M - 1) grow = M - 1;
      const ushort* g = A + ((long)(k >> 5) * M + grow) * 32 + (k & 31);
      gload_lds16(g, &smem[(is * 256 + wave * 64) * 8]);
    }
    #pragma unroll
    for (int is = 0; is < 4; ++is) {
      int s = is * 256 + tid;
      int row = s >> 3;
      int ch = (s & 7) ^ (row & 7);
      const ushort* g = WT + (long)(n0 + row) * K + k0 + ch * 8;
      gload_lds16(g, &smem[8192 + (is * 256 + wave * 64) * 8]);
    }
    asm volatile("s_waitcnt vmcnt(0)" ::: "memory");
    __syncthreads();
    #pragma unroll
    for (int ks = 0; ks < 2; ++ks) {
      h8_t af[4], bfr[4];
      #pragma unroll
      for (int mi = 0; mi < 4; ++mi) {
        int row = wm * 64 + mi * 16 + (lane & 15);
        int ch = (ks * 4 + (lane >> 4)) ^ (row & 7);
        af[mi] = *(const h8_t*)(&smem[row * 64 + ch * 8]);
      }
      #pragma unroll
      for (int ni = 0; ni < 4; ++ni) {
        int row = wn * 64 + ni * 16 + (lane & 15);
        int ch = (ks * 4 + (lane >> 4)) ^ (row & 7);
        bfr[ni] = *(const h8_t*)(&smem[8192 + row * 64 + ch * 8]);
      }
      #pragma unroll
      for (int mi = 0; mi < 4; ++mi)
        #pragma unroll
        for (int ni = 0; ni < 4; ++ni)
          acc[mi][ni] = mfma16(af[mi], bfr[ni], acc[mi][ni]);
    }
  }
  #pragma unroll
  for (int ni = 0; ni < 4; ++ni) {
    int col = n0 + wn * 64 + ni * 16 + (lane & 15);
    float bb = bias[col];
    #pragma unroll
    for (int mi = 0; mi < 4; ++mi) {
      #pragma unroll
      for (int r = 0; r < 4; ++r) {
        int row = m0 + wm * 64 + mi * 16 + (lane >> 4) * 4 + r;
        if (row < M) {
          float v = fmaxf(acc[mi][ni][r] + bb, 0.0f);
          if (OUTCB)
            outb[((long)(col >> 5) * M + row) * 32 + (col & 31)] = f2h(v);
          else
            outb[(long)row * HIDC + col] = f2h(v);
        }
      }
    }
  }
}

// ---------------- pool via binary search on sorted batch ----------------
#define POOL_SPLIT 8
__global__ __launch_bounds__(HIDC) void pool_range_f16(const ushort* __restrict__ h,
                                                       const int* __restrict__ batch,
                                                       float* __restrict__ gsum, int N) {
  int g = blockIdx.x;
  int s = blockIdx.y;
  int c = threadIdx.x;
  int s0 = lbound(batch, N, g);
  int s1 = lbound(batch, N, g + 1);
  int len = s1 - s0;
  int chunk = (len + POOL_SPLIT - 1) / POOL_SPLIT;
  int i0 = s0 + s * chunk;
  int i1 = min(i0 + chunk, s1);
  float acc = 0.0f;
  for (int i = i0; i < i1; ++i) acc += h2f(h[(long)i * HIDC + c]);
  if (i1 > i0) atomicAdd(&gsum[g * HIDC + c], acc);
}

// ---------------- final MLP + log_softmax ----------------
__global__ __launch_bounds__(64) void mlp_kernel(
    const float* __restrict__ gsum, const int* __restrict__ batch,
    const float* __restrict__ Wl1, const float* __restrict__ bl1,
    const float* __restrict__ Wl2, const float* __restrict__ bl2,
    float* __restrict__ out, int N) {
  __shared__ float g[HIDC];
  __shared__ float hid[64];
  __shared__ float logits[NCLS];
  __shared__ float red[2];
  int i = blockIdx.x;
  int t = threadIdx.x;
  int cnt = lbound(batch, N, i + 1) - lbound(batch, N, i);
  float inv = 1.0f / fmaxf((float)cnt, 1.0f);
  for (int c = t; c < HIDC; c += 64) g[c] = gsum[i * HIDC + c] * inv;
  __syncthreads();
  float acc = bl1[t];
  for (int c = 0; c < HIDC; ++c) acc = fmaf(g[c], Wl1[c * 64 + t], acc);
  hid[t] = fmaxf(acc, 0.0f);
  __syncthreads();
  if (t < NCLS) {
    float l = bl2[t];
    for (int c = 0; c < 64; ++c) l = fmaf(hid[c], Wl2[c * NCLS + t], l);
    logits[t] = l;
  }
  __syncthreads();
  if (t == 0) {
    float m = -1e30f;
    for (int k = 0; k < NCLS; ++k) m = fmaxf(m, logits[k]);
    float s = 0.f;
    for (int k = 0; k < NCLS; ++k) s += expf(logits[k] - m);
    red[0] = m;
    red[1] = logf(s);
  }
  __syncthreads();
  if (t < NCLS) out[i * NCLS + t] = logits[t] - red[0] - red[1];
}

extern "C" void kernel_launch(void* const* d_in, const int* in_sizes, int n_in,
                              void* d_out, int out_size, void* d_ws, size_t ws_size,
                              hipStream_t stream) {
  const float* x = (const float*)d_in[0];
  const int* edge_index = (const int*)d_in[1];
  const int* batch = (const int*)d_in[2];
  const float* W1 = (const float*)d_in[3];
  const float* b1 = (const float*)d_in[4];
  const float* W2 = (const float*)d_in[5];
  const float* b2 = (const float*)d_in[6];
  const float* Wl1 = (const float*)d_in[7];
  const float* bl1 = (const float*)d_in[8];
  const float* Wl2 = (const float*)d_in[9];
  const float* bl2 = (const float*)d_in[10];
  float* out = (float*)d_out;

  const int N = in_sizes[0] / INC;     // 50000
  const int E = in_sizes[1] / 2;       // 1600000
  const int* erow = edge_index;
  const int* ecol = edge_index + E;

  char* p = (char*)d_ws;
  auto alloc = [&](size_t bytes) {
    void* r = (void*)p;
    p += (bytes + 255) & ~(size_t)255;
    return r;
  };
  float* dis = (float*)alloc((size_t)N * 4);
  int* offsets = (int*)alloc((size_t)(N + 1) * 4);
  unsigned* ew = (unsigned*)alloc((size_t)E * 4);
  unsigned* part = (unsigned*)alloc((size_t)E * 4);
  int* hist = (int*)alloc((size_t)(NB * NBLK) * 4);
  int* histBase = (int*)alloc((size_t)(NB * NBLK + 1) * 4);
  float* gsum = (float*)alloc((size_t)NG * HIDC * 4);
  int* blockTotals = (int*)alloc((size_t)256 * 4);
  ushort* W1T = (ushort*)alloc((size_t)INC * HIDC * 2);
  ushort* W2T = (ushort*)alloc((size_t)HIDC * HIDC * 2);
  unsigned* x_cb = (unsigned*)alloc((size_t)N * INC * 2);      // [4][N][16u]
  unsigned* agg1_cb = (unsigned*)alloc((size_t)N * INC * 2);   // [4][N][16u]
  unsigned* h1_cb = (unsigned*)alloc((size_t)N * HIDC * 2);    // [8][N][16u]
  unsigned* agg2_cb = (unsigned*)alloc((size_t)N * HIDC * 2);  // [8][N][16u]
  ushort* h2 = (ushort*)x_cb;  // reuse (x_cb+agg1_cb dead after GEMM1)

  hipMemsetAsync(gsum, 0, (size_t)NG * HIDC * 4, stream);

  // bucketed CSR build
  const int chunk = (E + NBLK - 1) / NBLK;
  edge_hist<<<NBLK, 256, 0, stream>>>(ecol, hist, E, chunk);
  {
    const int nh = NB * NBLK;
    const int nbh = (nh + SCAN_VPB - 1) / SCAN_VPB;
    scanA<<<nbh, SCAN_T, 0, stream>>>(hist, histBase, blockTotals, nh);
    scanB<<<1, 64, 0, stream>>>(blockTotals, nbh);
    scanC<<<(nh + 255) / 256, 256, 0, stream>>>(histBase, blockTotals, nh);
  }
  edge_partition<<<NBLK, 256, 0, stream>>>(erow, ecol, histBase, part, E, chunk);
  bucket_off_dis<<<NB, 256, 0, stream>>>(part, histBase, offsets, dis, N);
  bucket_csr_ew<<<NB, 256, 0, stream>>>(part, histBase, offsets, dis, ew, N);

  // fused casts (x + both weights)
  {
    int tot = N * 64 + INC * HIDC + HIDC * HIDC;
    cast_all<<<(tot + 255) / 256, 256, 0, stream>>>(x, x_cb, W1, W1T, W2, W2T, N);
  }

  // layer 1: XCD-pinned cb aggregate (4 slices), GEMM -> h1 cb
  {
    const int nb2 = (N + 63) / 64;
    aggregate_cb<1><<<nb2 << 3, 256, 0, stream>>>(
        (const uint2*)x_cb, dis, offsets, ew, (uint2*)agg1_cb, N);
  }
  {
    dim3 grid((N + 127) / 128, HIDC / 128);
    gemm_mfma<INC, true><<<grid, 256, 0, stream>>>(
        (const ushort*)agg1_cb, W1T, b1, (ushort*)h1_cb, N);
  }
  // layer 2: XCD-pinned cb aggregate (8 slices), GEMM -> h2 row-major
  {
    const int nodeblks = (N + 31) / 32;
    aggregate_cb<0><<<nodeblks << 3, 256, 0, stream>>>(
        (const uint2*)h1_cb, dis, offsets, ew, (uint2*)agg2_cb, N);
  }
  {
    dim3 grid((N + 127) / 128, HIDC / 128);
    gemm_mfma<HIDC, false><<<grid, 256, 0, stream>>>(
        (const ushort*)agg2_cb, W2T, b2, h2, N);
  }
  // pool + MLP (binary-search batch; no find_bounds kernel)
  {
    dim3 pgrid(NG, POOL_SPLIT);
    pool_range_f16<<<pgrid, HIDC, 0, stream>>>(h2, batch, gsum, N);
  }
  mlp_kernel<<<NG, 64, 0, stream>>>(gsum, batch, Wl1, bl1, Wl2, bl2, out, N);
}